// Round 1
// baseline (362.379 us; speedup 1.0000x reference)
//
#include <hip/hip_runtime.h>
#include <hip/hip_bf16.h>
#include <math.h>

// ---------------------------------------------------------------------------
// Neural3DHMM: full pipeline on MI355X (gfx950)
//   4x residual MLP -> priors / sparse-7 transition softmax / emission head
//   emission logsumexp over V=10000 fused into bf16 MFMA GEMM epilogue
//   5x5 replicate-pad log-mean pooling only at used story-token columns
//   single-kernel HMM forward recursion (score in LDS, 8 blocks)
// ---------------------------------------------------------------------------

typedef __bf16 bf16_t;
typedef __bf16 bf16x8 __attribute__((ext_vector_type(8)));
typedef float  floatx4 __attribute__((ext_vector_type(4)));
typedef short  short8  __attribute__((ext_vector_type(8)));

#define S_TOT 2048
#define NT_LSE 157   // ceil(10000/64); 157*64 = 10048 (tok_emb bf16 padded to this)

// ------------------------------ conversions --------------------------------

struct CJob { const float* src; void* dst; int srows, scols, drows, dcols, tobf; };
struct CJobs { CJob j[12]; };

__global__ void conv_k(CJobs jobs) {
    CJob job = jobs.j[blockIdx.y];
    int total = job.drows * job.dcols;
    for (int idx = blockIdx.x * 256 + threadIdx.x; idx < total; idx += gridDim.x * 256) {
        int r = idx / job.dcols;
        int c = idx - r * job.dcols;
        float v = (r < job.srows && c < job.scols) ? job.src[(size_t)r * job.scols + c] : 0.f;
        if (job.tobf) ((bf16_t*)job.dst)[idx] = (bf16_t)v;
        else          ((float*)job.dst)[idx]  = v;
    }
}

// gather tok_emb rows for each story slot (1536 slots); pad token -> zeros
__global__ void gather_k(const float* __restrict__ tok_emb, const int* __restrict__ stories,
                         bf16_t* __restrict__ dst) {
    int j = blockIdx.x;           // slot
    int c = threadIdx.x;          // 0..127
    int tok = stories[j];
    float v = (tok < 10000 && c < 100) ? tok_emb[(size_t)tok * 100 + c] : 0.f;
    dst[(size_t)j * 128 + c] = (bf16_t)v;
}

// ------------------------------ bf16 MFMA GEMM -----------------------------
// C[m][n] = sum_k A[m][k] * Bt[n][k]   (A: MxK row-major, Bt: NxK row-major)
// EPI 0: store f32 C
// EPI 1: v=relu(c+bias[n]); store f32 C and bf16 Cbf
// EPI 2: v=relu(c+bias[n]) + addm[m][n]; store f32 C
// EPI 3: per-row (max, sum exp) partials over this 64-col tile -> Pmax/Psum
#define BM 64
#define BN 64
#define BKK 32
#define LDT 48   // LDS row stride in bf16 (96B: 16B-aligned, 4-way max bank conflict)

template<int EPI>
__global__ __launch_bounds__(256) void gemm_k(
    const bf16_t* __restrict__ A, int lda,
    const bf16_t* __restrict__ Bt, int ldb,
    int N, int K,
    float* __restrict__ C, int ldc,
    const float* __restrict__ bias,
    const float* __restrict__ addm, int ldadd,
    bf16_t* __restrict__ Cbf, int ldcb,
    float* __restrict__ Pmax, float* __restrict__ Psum)
{
    __shared__ alignas(16) bf16_t As[BM * LDT];
    __shared__ alignas(16) bf16_t Bs[BN * LDT];
    const int tid  = threadIdx.x;
    const int m0   = blockIdx.x * BM;
    const int n0   = blockIdx.y * BN;
    const int lane = tid & 63, wave = tid >> 6;
    const int wm = (wave & 1) * 32, wn = (wave >> 1) * 32;
    const int sr = tid >> 2, scc = (tid & 3) * 8;
    const int qm = lane & 15, qk = (lane >> 4) * 8;

    floatx4 acc[2][2];
    floatx4 zf = {0.f, 0.f, 0.f, 0.f};
#pragma unroll
    for (int i = 0; i < 2; i++)
#pragma unroll
        for (int j = 0; j < 2; j++) acc[i][j] = zf;

    for (int k0 = 0; k0 < K; k0 += BKK) {
        *(short8*)&As[sr * LDT + scc] = *(const short8*)&A[(size_t)(m0 + sr) * lda + k0 + scc];
        *(short8*)&Bs[sr * LDT + scc] = *(const short8*)&Bt[(size_t)(n0 + sr) * ldb + k0 + scc];
        __syncthreads();
        bf16x8 a[2], b[2];
        a[0] = *(const bf16x8*)&As[(wm + qm) * LDT + qk];
        a[1] = *(const bf16x8*)&As[(wm + 16 + qm) * LDT + qk];
        b[0] = *(const bf16x8*)&Bs[(wn + qm) * LDT + qk];
        b[1] = *(const bf16x8*)&Bs[(wn + 16 + qm) * LDT + qk];
#pragma unroll
        for (int mi = 0; mi < 2; mi++)
#pragma unroll
            for (int ni = 0; ni < 2; ni++)
                acc[mi][ni] = __builtin_amdgcn_mfma_f32_16x16x32_bf16(a[mi], b[ni], acc[mi][ni], 0, 0, 0);
        __syncthreads();
    }

    const int cl = lane & 15, rq = (lane >> 4) * 4;

    if constexpr (EPI == 3) {
        __shared__ float Cs[BM][BN + 1];
#pragma unroll
        for (int mi = 0; mi < 2; mi++)
#pragma unroll
            for (int ni = 0; ni < 2; ni++)
#pragma unroll
                for (int r = 0; r < 4; r++) {
                    int lm = wm + mi * 16 + rq + r;
                    int ln2 = wn + ni * 16 + cl;
                    Cs[lm][ln2] = (n0 + ln2 < N) ? acc[mi][ni][r] : -INFINITY;
                }
        __syncthreads();
        int trow = tid >> 2, part = tid & 3;
        float m = -INFINITY;
#pragma unroll
        for (int c = 0; c < 16; c++) m = fmaxf(m, Cs[trow][part * 16 + c]);
        m = fmaxf(m, __shfl_xor(m, 1));
        m = fmaxf(m, __shfl_xor(m, 2));
        float ss = 0.f;
#pragma unroll
        for (int c = 0; c < 16; c++) ss += __expf(Cs[trow][part * 16 + c] - m);
        ss += __shfl_xor(ss, 1);
        ss += __shfl_xor(ss, 2);
        if (part == 0) {
            Pmax[(size_t)blockIdx.y * S_TOT + m0 + trow] = m;
            Psum[(size_t)blockIdx.y * S_TOT + m0 + trow] = ss;
        }
    } else {
#pragma unroll
        for (int mi = 0; mi < 2; mi++)
#pragma unroll
            for (int ni = 0; ni < 2; ni++)
#pragma unroll
                for (int r = 0; r < 4; r++) {
                    int gm = m0 + wm + mi * 16 + rq + r;
                    int gn = n0 + wn + ni * 16 + cl;
                    if (gn < N) {
                        float v = acc[mi][ni][r];
                        if constexpr (EPI == 0) {
                            C[(size_t)gm * ldc + gn] = v;
                        } else if constexpr (EPI == 1) {
                            v = fmaxf(v + bias[gn], 0.f);
                            C[(size_t)gm * ldc + gn] = v;
                            Cbf[(size_t)gm * ldcb + gn] = (bf16_t)v;
                        } else {
                            v = fmaxf(v + bias[gn], 0.f) + addm[(size_t)gm * ldadd + gn];
                            C[(size_t)gm * ldc + gn] = v;
                        }
                    }
                }
    }
}

// ------------------------------ layernorm ----------------------------------
__global__ __launch_bounds__(256) void ln_k(
    const float* __restrict__ h, int ld, int dout,
    const float* __restrict__ g, const float* __restrict__ beta,
    float* __restrict__ of32, int ldo,
    bf16_t* __restrict__ obf, int ldob, int padN)
{
    __shared__ float red[256];
    int row = blockIdx.x, t = threadIdx.x;
    float hv = (t < dout) ? h[(size_t)row * ld + t] : 0.f;
    red[t] = hv;
    __syncthreads();
#pragma unroll
    for (int s = 128; s > 0; s >>= 1) { if (t < s) red[t] += red[t + s]; __syncthreads(); }
    float mu = red[0] / dout;
    __syncthreads();
    float d = (t < dout) ? (hv - mu) : 0.f;
    red[t] = d * d;
    __syncthreads();
#pragma unroll
    for (int s = 128; s > 0; s >>= 1) { if (t < s) red[t] += red[t + s]; __syncthreads(); }
    float var = red[0] / dout;
    float rstd = rsqrtf(var + 1e-5f);
    if (t < dout) {
        float y = d * rstd * g[t] + beta[t];
        if (of32) of32[(size_t)row * ldo + t] = y;
        if (obf)  obf[(size_t)row * ldob + t] = (bf16_t)y;
    } else if (obf && t < padN) {
        obf[(size_t)row * ldob + t] = (bf16_t)0.f;
    }
}

// ------------------------------ priors -------------------------------------
__global__ __launch_bounds__(256) void praw_k(const float* __restrict__ h0,
                                              const float* __restrict__ wo,
                                              const float* __restrict__ bo,
                                              float* __restrict__ praw)
{
    __shared__ float w[256];
    int t = threadIdx.x;
    w[t] = wo[t];
    __syncthreads();
    int s = blockIdx.x * 256 + t;
    const float4* hr = (const float4*)(h0 + (size_t)s * 256);
    const float4* wv = (const float4*)w;
    float acc = 0.f;
#pragma unroll 4
    for (int k = 0; k < 64; k++) {
        float4 a = hr[k]; float4 b = wv[k];
        acc += a.x * b.x + a.y * b.y + a.z * b.z + a.w * b.w;
    }
    praw[s] = acc + bo[0];
}

__global__ __launch_bounds__(1024) void prior_lse_k(const float* __restrict__ praw,
                                                    float* __restrict__ out)
{
    __shared__ float red[1024];
    int t = threadIdx.x;
    float a = praw[t], b = praw[t + 1024];
    red[t] = fmaxf(a, b);
    __syncthreads();
#pragma unroll
    for (int s = 512; s > 0; s >>= 1) { if (t < s) red[t] = fmaxf(red[t], red[t + s]); __syncthreads(); }
    float M = red[0];
    __syncthreads();
    red[t] = __expf(a - M) + __expf(b - M);
    __syncthreads();
#pragma unroll
    for (int s = 512; s > 0; s >>= 1) { if (t < s) red[t] += red[t + s]; __syncthreads(); }
    if (t == 0) out[0] = M + __logf(red[0]);
}

// --------------------- sparse transition (7 neighbors) ---------------------
__global__ __launch_bounds__(64) void trans_k(const float* __restrict__ hin,
                                              const float* __restrict__ hout,
                                              float* __restrict__ tr)
{
    const int OFFS[7] = {0, 1, -1, 16, -16, 256, 512};
    int j = blockIdx.x;
    int lane = threadIdx.x;
    float4 a = ((const float4*)(hin + (size_t)j * 256))[lane];
    float d[7];
#pragma unroll
    for (int k = 0; k < 7; k++) {
        int i = j + OFFS[k];
        float pdot = 0.f;
        if ((unsigned)i < 2048u) {
            float4 b = ((const float4*)(hout + (size_t)i * 256))[lane];
            pdot = a.x * b.x + a.y * b.y + a.z * b.z + a.w * b.w;
        }
#pragma unroll
        for (int o = 32; o > 0; o >>= 1) pdot += __shfl_down(pdot, o);
        d[k] = pdot;
    }
    if (lane == 0) {
        float m = -INFINITY;
#pragma unroll
        for (int k = 0; k < 7; k++) { int i = j + OFFS[k]; if ((unsigned)i < 2048u) m = fmaxf(m, d[k]); }
        float ss = 0.f;
#pragma unroll
        for (int k = 0; k < 7; k++) { int i = j + OFFS[k]; if ((unsigned)i < 2048u) ss += __expf(d[k] - m); }
        float l = __logf(ss);
#pragma unroll
        for (int k = 0; k < 7; k++) {
            int i = j + OFFS[k];
            tr[(size_t)j * 8 + k] = ((unsigned)i < 2048u) ? (d[k] - m - l) : -INFINITY;
        }
        tr[(size_t)j * 8 + 7] = -INFINITY;
    }
}

// --------------------- emission logsumexp finalize -------------------------
__global__ __launch_bounds__(256) void lse_fin_k(const float* __restrict__ Pmax,
                                                 const float* __restrict__ Psum,
                                                 float* __restrict__ lse)
{
    int s = blockIdx.x * 256 + threadIdx.x;
    float m = -INFINITY;
    for (int nb = 0; nb < NT_LSE; nb++) m = fmaxf(m, Pmax[(size_t)nb * S_TOT + s]);
    float ss = 0.f;
    for (int nb = 0; nb < NT_LSE; nb++)
        ss += Psum[(size_t)nb * S_TOT + s] * __expf(Pmax[(size_t)nb * S_TOT + s] - m);
    lse[s] = m + __logf(ss);
}

// --------------------- 5x5 replicate-pad log-mean pool ---------------------
// em[j][s] holds raw logits; subtract lse[s] (-> log_softmax), pool over the
// 16x16 (a,b) grid per z-slice (b first then a, matching the reference),
// subtract log(25), write back in place.
__global__ __launch_bounds__(256) void pool_k(float* __restrict__ em,
                                              const float* __restrict__ lse)
{
    __shared__ float sm[256];
    __shared__ float sm2[256];
    int j = blockIdx.x, z = blockIdx.y, t = threadIdx.x;
    int a = t >> 4, b = t & 15;
    size_t base = (size_t)j * S_TOT + (size_t)z * 256;
    float v = em[base + t] - lse[z * 256 + t];
    sm[t] = v;
    __syncthreads();
    float m = -INFINITY;
#pragma unroll
    for (int d = -2; d <= 2; d++) {
        int bb = b + d; bb = bb < 0 ? 0 : (bb > 15 ? 15 : bb);
        m = fmaxf(m, sm[a * 16 + bb]);
    }
    float ss = 0.f;
#pragma unroll
    for (int d = -2; d <= 2; d++) {
        int bb = b + d; bb = bb < 0 ? 0 : (bb > 15 ? 15 : bb);
        ss += __expf(sm[a * 16 + bb] - m);
    }
    sm2[t] = m + __logf(ss);
    __syncthreads();
    float m2 = -INFINITY;
#pragma unroll
    for (int d = -2; d <= 2; d++) {
        int aa = a + d; aa = aa < 0 ? 0 : (aa > 15 ? 15 : aa);
        m2 = fmaxf(m2, sm2[aa * 16 + b]);
    }
    float s2 = 0.f;
#pragma unroll
    for (int d = -2; d <= 2; d++) {
        int aa = a + d; aa = aa < 0 ? 0 : (aa > 15 ? 15 : aa);
        s2 += __expf(sm2[aa * 16 + b] - m2);
    }
    em[base + t] = m2 + __logf(s2) - 3.2188758248682006f;  // log(25)
}

// --------------------- per-(b,t) emission scores ---------------------------
__global__ __launch_bounds__(256) void emis_k(const float* __restrict__ em,
                                              const int* __restrict__ stories,
                                              float* __restrict__ emis)
{
    int bt = blockIdx.x, t = threadIdx.x;
    const int* st = stories + bt * 12;
    int toks[12];
#pragma unroll
    for (int l = 0; l < 12; l++) toks[l] = st[l];
#pragma unroll
    for (int i = 0; i < 8; i++) {
        int s = i * 256 + t;
        float acc = 0.f;
#pragma unroll
        for (int l = 0; l < 12; l++) {
            int tk = toks[l];
            if (tk < 10000) acc += em[(size_t)(bt * 12 + l) * S_TOT + s];
        }
        emis[(size_t)bt * S_TOT + s] = acc;
    }
}

// --------------------- HMM forward recursion -------------------------------
__global__ __launch_bounds__(1024) void fwd_k(const float* __restrict__ emm,
                                              const float* __restrict__ praw,
                                              const float* __restrict__ plse,
                                              const float* __restrict__ tr,
                                              float* __restrict__ out)
{
    const int OFFS[7] = {0, 1, -1, 16, -16, 256, 512};
    __shared__ float sc[2][S_TOT];
    int b = blockIdx.x, t = threadIdx.x;
    float pl = plse[0];
    const float* eb = emm + (size_t)b * 16 * S_TOT;
#pragma unroll
    for (int i = 0; i < 2; i++) {
        int j = i * 1024 + t;
        float v = eb[j] + praw[j] - pl;
        sc[0][j] = v;
        out[(size_t)b * S_TOT + j] = v;
    }
    __syncthreads();
    for (int tt = 1; tt < 16; tt++) {
        int cur = tt & 1, prv = cur ^ 1;
#pragma unroll
        for (int i = 0; i < 2; i++) {
            int j = i * 1024 + t;
            const float* trj = tr + (size_t)j * 8;
            float tv[7];
            float m = -INFINITY;
#pragma unroll
            for (int k = 0; k < 7; k++) {
                int ii = j + OFFS[k];
                if ((unsigned)ii < 2048u) {
                    float x = trj[k] + sc[prv][ii];
                    tv[k] = x;
                    m = fmaxf(m, x);
                } else {
                    tv[k] = -INFINITY;
                }
            }
            float ss = 0.f;
#pragma unroll
            for (int k = 0; k < 7; k++) ss += __expf(tv[k] - m);
            float v = eb[(size_t)tt * S_TOT + j] + m + __logf(ss);
            sc[cur][j] = v;
            out[(size_t)tt * (8 * S_TOT) + (size_t)b * S_TOT + j] = v;
        }
        __syncthreads();
    }
}

// ---------------------------------------------------------------------------
extern "C" void kernel_launch(void* const* d_in, const int* in_sizes, int n_in,
                              void* d_out, int out_size, void* d_ws, size_t ws_size,
                              hipStream_t stream)
{
    (void)in_sizes; (void)n_in; (void)out_size; (void)ws_size;
    const float* state_emb  = (const float*)d_in[0];
    const float* tok_emb    = (const float*)d_in[1];
    const float* start_w1   = (const float*)d_in[2];
    const float* start_b1   = (const float*)d_in[3];
    const float* start_w2   = (const float*)d_in[4];
    const float* start_b2   = (const float*)d_in[5];
    const float* start_g    = (const float*)d_in[6];
    const float* start_beta = (const float*)d_in[7];
    const float* start_wo   = (const float*)d_in[8];
    const float* start_bo   = (const float*)d_in[9];
    const float* tin_w1     = (const float*)d_in[10];
    const float* tin_b1     = (const float*)d_in[11];
    const float* tin_w2     = (const float*)d_in[12];
    const float* tin_b2     = (const float*)d_in[13];
    const float* tin_g      = (const float*)d_in[14];
    const float* tin_beta   = (const float*)d_in[15];
    const float* tout_w1    = (const float*)d_in[16];
    const float* tout_b1    = (const float*)d_in[17];
    const float* tout_w2    = (const float*)d_in[18];
    const float* tout_b2    = (const float*)d_in[19];
    const float* tout_g     = (const float*)d_in[20];
    const float* tout_beta  = (const float*)d_in[21];
    const float* emit_w1    = (const float*)d_in[22];
    const float* emit_b1    = (const float*)d_in[23];
    const float* emit_w2    = (const float*)d_in[24];
    const float* emit_b2    = (const float*)d_in[25];
    const float* emit_g     = (const float*)d_in[26];
    const float* emit_beta  = (const float*)d_in[27];
    const int*   stories    = (const int*)d_in[28];
    float* out = (float*)d_out;

    char* p = (char*)d_ws;
    auto carve = [&](size_t bytes) -> char* {
        char* r = p;
        p += (bytes + 255) & ~(size_t)255;
        return r;
    };

    bf16_t* se_bf   = (bf16_t*)carve((size_t)2048 * 256 * 2);
    bf16_t* tok_bf  = (bf16_t*)carve((size_t)10048 * 128 * 2);
    bf16_t* w_s1    = (bf16_t*)carve((size_t)256 * 256 * 2);
    bf16_t* w_s2    = (bf16_t*)carve((size_t)256 * 256 * 2);
    bf16_t* w_i1    = (bf16_t*)carve((size_t)256 * 256 * 2);
    bf16_t* w_i2    = (bf16_t*)carve((size_t)256 * 256 * 2);
    bf16_t* w_o1    = (bf16_t*)carve((size_t)256 * 256 * 2);
    bf16_t* w_o2    = (bf16_t*)carve((size_t)256 * 256 * 2);
    bf16_t* w_e1    = (bf16_t*)carve((size_t)128 * 256 * 2);
    bf16_t* w_e2    = (bf16_t*)carve((size_t)128 * 128 * 2);
    float*  eb1     = (float*)carve(128 * 4);
    float*  eb2     = (float*)carve(128 * 4);
    float*  x1f     = (float*)carve((size_t)2048 * 256 * 4);
    bf16_t* x1b     = (bf16_t*)carve((size_t)2048 * 256 * 2);
    float*  htmp    = (float*)carve((size_t)2048 * 256 * 4);
    float*  hs0     = (float*)carve((size_t)2048 * 256 * 4);
    float*  hin     = (float*)carve((size_t)2048 * 256 * 4);
    float*  hout    = (float*)carve((size_t)2048 * 256 * 4);
    bf16_t* hemit   = (bf16_t*)carve((size_t)2048 * 128 * 2);
    float*  praw    = (float*)carve((size_t)2048 * 4);
    float*  plse    = (float*)carve(256);
    float*  trans   = (float*)carve((size_t)2048 * 8 * 4);
    bf16_t* tokused = (bf16_t*)carve((size_t)1536 * 128 * 2);
    float*  em      = (float*)carve((size_t)1536 * 2048 * 4);
    float*  pmax    = (float*)carve((size_t)NT_LSE * 2048 * 4);
    float*  psum    = (float*)carve((size_t)NT_LSE * 2048 * 4);
    float*  lse     = (float*)carve((size_t)2048 * 4);
    float*  emis    = (float*)carve((size_t)128 * 2048 * 4);

    // 1. convert / pad everything to bf16 (zero-padded K to multiples of 32)
    CJobs jobs;
    jobs.j[0]  = {state_emb, se_bf, 2048, 256, 2048, 256, 1};
    jobs.j[1]  = {tok_emb,   tok_bf, 10000, 100, 10048, 128, 1};
    jobs.j[2]  = {start_w1,  w_s1, 256, 256, 256, 256, 1};
    jobs.j[3]  = {start_w2,  w_s2, 256, 256, 256, 256, 1};
    jobs.j[4]  = {tin_w1,    w_i1, 256, 256, 256, 256, 1};
    jobs.j[5]  = {tin_w2,    w_i2, 256, 256, 256, 256, 1};
    jobs.j[6]  = {tout_w1,   w_o1, 256, 256, 256, 256, 1};
    jobs.j[7]  = {tout_w2,   w_o2, 256, 256, 256, 256, 1};
    jobs.j[8]  = {emit_w1,   w_e1, 100, 256, 128, 256, 1};
    jobs.j[9]  = {emit_w2,   w_e2, 100, 100, 128, 128, 1};
    jobs.j[10] = {emit_b1,   eb1, 1, 100, 1, 128, 0};
    jobs.j[11] = {emit_b2,   eb2, 1, 100, 1, 128, 0};
    conv_k<<<dim3(160, 12), 256, 0, stream>>>(jobs);
    gather_k<<<1536, 128, 0, stream>>>(tok_emb, stories, tokused);

    // 2. start residual -> priors
    gemm_k<1><<<dim3(32, 4), 256, 0, stream>>>(se_bf, 256, w_s1, 256, 256, 256,
                                               x1f, 256, start_b1, nullptr, 0, x1b, 256, nullptr, nullptr);
    gemm_k<2><<<dim3(32, 4), 256, 0, stream>>>(x1b, 256, w_s2, 256, 256, 256,
                                               htmp, 256, start_b2, x1f, 256, nullptr, 0, nullptr, nullptr);
    ln_k<<<2048, 256, 0, stream>>>(htmp, 256, 256, start_g, start_beta, hs0, 256, nullptr, 0, 0);
    praw_k<<<8, 256, 0, stream>>>(hs0, start_wo, start_bo, praw);
    prior_lse_k<<<1, 1024, 0, stream>>>(praw, plse);

    // 3. tin / tout residuals -> sparse transition log-softmax
    gemm_k<1><<<dim3(32, 4), 256, 0, stream>>>(se_bf, 256, w_i1, 256, 256, 256,
                                               x1f, 256, tin_b1, nullptr, 0, x1b, 256, nullptr, nullptr);
    gemm_k<2><<<dim3(32, 4), 256, 0, stream>>>(x1b, 256, w_i2, 256, 256, 256,
                                               htmp, 256, tin_b2, x1f, 256, nullptr, 0, nullptr, nullptr);
    ln_k<<<2048, 256, 0, stream>>>(htmp, 256, 256, tin_g, tin_beta, hin, 256, nullptr, 0, 0);

    gemm_k<1><<<dim3(32, 4), 256, 0, stream>>>(se_bf, 256, w_o1, 256, 256, 256,
                                               x1f, 256, tout_b1, nullptr, 0, x1b, 256, nullptr, nullptr);
    gemm_k<2><<<dim3(32, 4), 256, 0, stream>>>(x1b, 256, w_o2, 256, 256, 256,
                                               htmp, 256, tout_b2, x1f, 256, nullptr, 0, nullptr, nullptr);
    ln_k<<<2048, 256, 0, stream>>>(htmp, 256, 256, tout_g, tout_beta, hout, 256, nullptr, 0, 0);

    trans_k<<<2048, 64, 0, stream>>>(hin, hout, trans);

    // 4. emit residual -> h_emit (bf16, K-padded)
    gemm_k<1><<<dim3(32, 2), 256, 0, stream>>>(se_bf, 256, w_e1, 256, 128, 256,
                                               x1f, 128, eb1, nullptr, 0, x1b, 128, nullptr, nullptr);
    gemm_k<2><<<dim3(32, 2), 256, 0, stream>>>(x1b, 128, w_e2, 128, 128, 128,
                                               htmp, 128, eb2, x1f, 128, nullptr, 0, nullptr, nullptr);
    ln_k<<<2048, 256, 0, stream>>>(htmp, 128, 100, emit_g, emit_beta, nullptr, 0, hemit, 128, 128);

    // 5. emission logsumexp over V=10000 (fused GEMM partials) + finalize
    gemm_k<3><<<dim3(32, NT_LSE), 256, 0, stream>>>(hemit, 128, tok_bf, 128, 10000, 128,
                                                    nullptr, 0, nullptr, nullptr, 0, nullptr, 0, pmax, psum);
    lse_fin_k<<<8, 256, 0, stream>>>(pmax, psum, lse);

    // 6. logits at used tokens, pool, per-(b,t) emission scores
    gemm_k<0><<<dim3(24, 32), 256, 0, stream>>>(tokused, 128, hemit, 128, 2048, 128,
                                                em, 2048, nullptr, nullptr, 0, nullptr, 0, nullptr, nullptr);
    pool_k<<<dim3(1536, 8), 256, 0, stream>>>(em, lse);
    emis_k<<<128, 256, 0, stream>>>(em, stories, emis);

    // 7. forward recursion -> [T,B,S] output
    fwd_k<<<8, 1024, 0, stream>>>(emis, praw, plse, trans, out);
}

// Round 2
// 290.692 us; speedup vs baseline: 1.2466x; 1.2466x over previous
//
#include <hip/hip_runtime.h>
#include <hip/hip_bf16.h>
#include <math.h>

// ---------------------------------------------------------------------------
// Neural3DHMM on MI355X (gfx950) — round 2
//   batched residual MLPs (one stage-1 GEMM, one stage-2 GEMM, one LN, z/y-indexed)
//   praw fused into LN epilogue; emission LSE fused into GEMM epilogue
//   fwd recursion with register-preloaded emissions/trans (LDS-only inner loop)
// ---------------------------------------------------------------------------

typedef __bf16 bf16_t;
typedef __bf16 bf16x8 __attribute__((ext_vector_type(8)));
typedef float  floatx4 __attribute__((ext_vector_type(4)));
typedef short  short8  __attribute__((ext_vector_type(8)));

#define S_TOT 2048
#define NT_LSE 157   // ceil(10000/64)

// ------------------------------ conversions --------------------------------

struct CJob { const float* src; void* dst; int srows, scols, drows, dcols, tobf; };
struct CJobs { CJob j[12]; };

__global__ void conv_k(CJobs jobs) {
    CJob job = jobs.j[blockIdx.y];
    int total = job.drows * job.dcols;
    for (int idx = blockIdx.x * 256 + threadIdx.x; idx < total; idx += gridDim.x * 256) {
        int r = idx / job.dcols;
        int c = idx - r * job.dcols;
        float v = (r < job.srows && c < job.scols) ? job.src[(size_t)r * job.scols + c] : 0.f;
        if (job.tobf) ((bf16_t*)job.dst)[idx] = (bf16_t)v;
        else          ((float*)job.dst)[idx]  = v;
    }
}

__global__ void gather_k(const float* __restrict__ tok_emb, const int* __restrict__ stories,
                         bf16_t* __restrict__ dst) {
    int j = blockIdx.x;
    int c = threadIdx.x;
    int tok = stories[j];
    float v = (tok < 10000 && c < 100) ? tok_emb[(size_t)tok * 100 + c] : 0.f;
    dst[(size_t)j * 128 + c] = (bf16_t)v;
}

// ------------------------------ bf16 MFMA GEMM (batched) -------------------
// C[m][n] = sum_k A[m][k] * Bt[n][k]
// EPI 0: store f32 C
// EPI 1: v=relu(c+bias[n]); store f32 C and bf16 Cbf
// EPI 2: v=relu(c+bias[n]) + addm[m][n]; store f32 C
// EPI 3: per-row (max,sumexp) partials over this 64-col tile -> Pmax/Psum
struct GJob {
    const bf16_t* A; int lda;
    const bf16_t* Bt; int ldb;
    int N, K;
    float* C; int ldc;
    const float* bias;
    const float* addm; int ldadd;
    bf16_t* Cbf; int ldcb;
    float* Pmax; float* Psum;
};
struct GJobs { GJob j[4]; };

#define BM 64
#define BN 64
#define LDT 72   // 64+8 bf16: 144B stride -> rows stagger 4 banks, 2-way (free)

template<int EPI>
__global__ __launch_bounds__(256) void gemm_k(GJobs jobs) {
    GJob jb = jobs.j[blockIdx.z];
    const int m0 = blockIdx.x * BM;
    const int n0 = blockIdx.y * BN;
    if (n0 >= jb.N) return;

    __shared__ alignas(16) bf16_t As[BM * LDT];
    __shared__ alignas(16) bf16_t Bs[BN * LDT];
    const int tid  = threadIdx.x;
    const int lane = tid & 63, wave = tid >> 6;
    const int wm = (wave & 1) * 32, wn = (wave >> 1) * 32;
    const int sr = tid >> 2, scc = (tid & 3) * 16;
    const int qm = lane & 15, qk = (lane >> 4) * 8;

    floatx4 acc[2][2];
    floatx4 zf = {0.f, 0.f, 0.f, 0.f};
#pragma unroll
    for (int i = 0; i < 2; i++)
#pragma unroll
        for (int j = 0; j < 2; j++) acc[i][j] = zf;

    for (int k0 = 0; k0 < jb.K; k0 += 64) {
        const bf16_t* Ar = jb.A + (size_t)(m0 + sr) * jb.lda + k0 + scc;
        const bf16_t* Br = jb.Bt + (size_t)(n0 + sr) * jb.ldb + k0 + scc;
        *(short8*)&As[sr * LDT + scc]     = *(const short8*)&Ar[0];
        *(short8*)&As[sr * LDT + scc + 8] = *(const short8*)&Ar[8];
        *(short8*)&Bs[sr * LDT + scc]     = *(const short8*)&Br[0];
        *(short8*)&Bs[sr * LDT + scc + 8] = *(const short8*)&Br[8];
        __syncthreads();
#pragma unroll
        for (int kk = 0; kk < 2; kk++) {
            int qo = kk * 32 + qk;
            bf16x8 a[2], b[2];
            a[0] = *(const bf16x8*)&As[(wm + qm) * LDT + qo];
            a[1] = *(const bf16x8*)&As[(wm + 16 + qm) * LDT + qo];
            b[0] = *(const bf16x8*)&Bs[(wn + qm) * LDT + qo];
            b[1] = *(const bf16x8*)&Bs[(wn + 16 + qm) * LDT + qo];
#pragma unroll
            for (int mi = 0; mi < 2; mi++)
#pragma unroll
                for (int ni = 0; ni < 2; ni++)
                    acc[mi][ni] = __builtin_amdgcn_mfma_f32_16x16x32_bf16(a[mi], b[ni], acc[mi][ni], 0, 0, 0);
        }
        __syncthreads();
    }

    const int cl = lane & 15, rq = (lane >> 4) * 4;

    if constexpr (EPI == 3) {
        __shared__ float Cs[BM][BN + 1];
#pragma unroll
        for (int mi = 0; mi < 2; mi++)
#pragma unroll
            for (int ni = 0; ni < 2; ni++)
#pragma unroll
                for (int r = 0; r < 4; r++) {
                    int lm = wm + mi * 16 + rq + r;
                    int ln2 = wn + ni * 16 + cl;
                    Cs[lm][ln2] = (n0 + ln2 < jb.N) ? acc[mi][ni][r] : -INFINITY;
                }
        __syncthreads();
        int trow = tid >> 2, part = tid & 3;
        float m = -INFINITY;
#pragma unroll
        for (int c = 0; c < 16; c++) m = fmaxf(m, Cs[trow][part * 16 + c]);
        m = fmaxf(m, __shfl_xor(m, 1));
        m = fmaxf(m, __shfl_xor(m, 2));
        float ss = 0.f;
#pragma unroll
        for (int c = 0; c < 16; c++) ss += __expf(Cs[trow][part * 16 + c] - m);
        ss += __shfl_xor(ss, 1);
        ss += __shfl_xor(ss, 2);
        if (part == 0) {
            jb.Pmax[(size_t)blockIdx.y * S_TOT + m0 + trow] = m;
            jb.Psum[(size_t)blockIdx.y * S_TOT + m0 + trow] = ss;
        }
    } else {
#pragma unroll
        for (int mi = 0; mi < 2; mi++)
#pragma unroll
            for (int ni = 0; ni < 2; ni++)
#pragma unroll
                for (int r = 0; r < 4; r++) {
                    int gm = m0 + wm + mi * 16 + rq + r;
                    int gn = n0 + wn + ni * 16 + cl;
                    if (gn < jb.N) {
                        float v = acc[mi][ni][r];
                        if constexpr (EPI == 0) {
                            jb.C[(size_t)gm * jb.ldc + gn] = v;
                        } else if constexpr (EPI == 1) {
                            v = fmaxf(v + jb.bias[gn], 0.f);
                            jb.C[(size_t)gm * jb.ldc + gn] = v;
                            jb.Cbf[(size_t)gm * jb.ldcb + gn] = (bf16_t)v;
                        } else {
                            v = fmaxf(v + jb.bias[gn], 0.f) + jb.addm[(size_t)gm * jb.ldadd + gn];
                            jb.C[(size_t)gm * jb.ldc + gn] = v;
                        }
                    }
                }
    }
}

// ------------------------------ layernorm (batched, praw fused) ------------
struct LJob {
    const float* h; int ld, dout;
    const float* g; const float* beta;
    float* of32; int ldo;
    bf16_t* obf; int ldob; int padN;
    const float* wo; const float* bo; float* praw;
};
struct LJobs { LJob j[4]; };

__global__ __launch_bounds__(256) void ln_k(LJobs jobs) {
    LJob jb = jobs.j[blockIdx.y];
    __shared__ float red[256];
    int row = blockIdx.x, t = threadIdx.x;
    float hv = (t < jb.dout) ? jb.h[(size_t)row * jb.ld + t] : 0.f;
    red[t] = hv;
    __syncthreads();
#pragma unroll
    for (int s = 128; s > 0; s >>= 1) { if (t < s) red[t] += red[t + s]; __syncthreads(); }
    float mu = red[0] / jb.dout;
    __syncthreads();
    float d = (t < jb.dout) ? (hv - mu) : 0.f;
    red[t] = d * d;
    __syncthreads();
#pragma unroll
    for (int s = 128; s > 0; s >>= 1) { if (t < s) red[t] += red[t + s]; __syncthreads(); }
    float var = red[0] / jb.dout;
    float rstd = rsqrtf(var + 1e-5f);
    float y = 0.f;
    if (t < jb.dout) {
        y = d * rstd * jb.g[t] + jb.beta[t];
        if (jb.of32) jb.of32[(size_t)row * jb.ldo + t] = y;
        if (jb.obf)  jb.obf[(size_t)row * jb.ldob + t] = (bf16_t)y;
    } else if (jb.obf && t < jb.padN) {
        jb.obf[(size_t)row * jb.ldob + t] = (bf16_t)0.f;
    }
    if (jb.wo) {
        __syncthreads();
        red[t] = (t < jb.dout) ? y * jb.wo[t] : 0.f;
        __syncthreads();
#pragma unroll
        for (int s = 128; s > 0; s >>= 1) { if (t < s) red[t] += red[t + s]; __syncthreads(); }
        if (t == 0) jb.praw[row] = red[0] + jb.bo[0];
    }
}

// ------------------------------ prior logsumexp ----------------------------
__global__ __launch_bounds__(1024) void prior_lse_k(const float* __restrict__ praw,
                                                    float* __restrict__ out)
{
    __shared__ float red[1024];
    int t = threadIdx.x;
    float a = praw[t], b = praw[t + 1024];
    red[t] = fmaxf(a, b);
    __syncthreads();
#pragma unroll
    for (int s = 512; s > 0; s >>= 1) { if (t < s) red[t] = fmaxf(red[t], red[t + s]); __syncthreads(); }
    float M = red[0];
    __syncthreads();
    red[t] = __expf(a - M) + __expf(b - M);
    __syncthreads();
#pragma unroll
    for (int s = 512; s > 0; s >>= 1) { if (t < s) red[t] += red[t + s]; __syncthreads(); }
    if (t == 0) out[0] = M + __logf(red[0]);
}

// --------------------- sparse transition (7 neighbors) ---------------------
__global__ __launch_bounds__(256) void trans_k(const float* __restrict__ hin,
                                               const float* __restrict__ hout,
                                               float* __restrict__ tr)
{
    const int OFFS[7] = {0, 1, -1, 16, -16, 256, 512};
    int j = blockIdx.x * 4 + (threadIdx.x >> 6);
    int lane = threadIdx.x & 63;
    float4 a = ((const float4*)(hin + (size_t)j * 256))[lane];
    float d[7];
#pragma unroll
    for (int k = 0; k < 7; k++) {
        int i = j + OFFS[k];
        float pdot = 0.f;
        if ((unsigned)i < 2048u) {
            float4 b = ((const float4*)(hout + (size_t)i * 256))[lane];
            pdot = a.x * b.x + a.y * b.y + a.z * b.z + a.w * b.w;
        }
#pragma unroll
        for (int o = 32; o > 0; o >>= 1) pdot += __shfl_down(pdot, o);
        d[k] = pdot;
    }
    if (lane == 0) {
        float m = -INFINITY;
#pragma unroll
        for (int k = 0; k < 7; k++) { int i = j + OFFS[k]; if ((unsigned)i < 2048u) m = fmaxf(m, d[k]); }
        float ss = 0.f;
#pragma unroll
        for (int k = 0; k < 7; k++) { int i = j + OFFS[k]; if ((unsigned)i < 2048u) ss += __expf(d[k] - m); }
        float l = __logf(ss);
#pragma unroll
        for (int k = 0; k < 7; k++) {
            int i = j + OFFS[k];
            tr[(size_t)j * 8 + k] = ((unsigned)i < 2048u) ? (d[k] - m - l) : -INFINITY;
        }
        tr[(size_t)j * 8 + 7] = -INFINITY;
    }
}

// --------------------- emission logsumexp finalize -------------------------
__global__ __launch_bounds__(256) void lse_fin_k(const float* __restrict__ Pmax,
                                                 const float* __restrict__ Psum,
                                                 float* __restrict__ lse)
{
    int s = blockIdx.x * 256 + threadIdx.x;
    float m = -INFINITY;
    for (int nb = 0; nb < NT_LSE; nb++) m = fmaxf(m, Pmax[(size_t)nb * S_TOT + s]);
    float ss = 0.f;
    for (int nb = 0; nb < NT_LSE; nb++)
        ss += Psum[(size_t)nb * S_TOT + s] * __expf(Pmax[(size_t)nb * S_TOT + s] - m);
    lse[s] = m + __logf(ss);
}

// --------------------- 5x5 replicate-pad log-mean pool ---------------------
__global__ __launch_bounds__(256) void pool_k(float* __restrict__ em,
                                              const float* __restrict__ lse)
{
    __shared__ float sm[256];
    __shared__ float sm2[256];
    int j = blockIdx.x, z = blockIdx.y, t = threadIdx.x;
    int a = t >> 4, b = t & 15;
    size_t base = (size_t)j * S_TOT + (size_t)z * 256;
    float v = em[base + t] - lse[z * 256 + t];
    sm[t] = v;
    __syncthreads();
    float m = -INFINITY;
#pragma unroll
    for (int d = -2; d <= 2; d++) {
        int bb = b + d; bb = bb < 0 ? 0 : (bb > 15 ? 15 : bb);
        m = fmaxf(m, sm[a * 16 + bb]);
    }
    float ss = 0.f;
#pragma unroll
    for (int d = -2; d <= 2; d++) {
        int bb = b + d; bb = bb < 0 ? 0 : (bb > 15 ? 15 : bb);
        ss += __expf(sm[a * 16 + bb] - m);
    }
    sm2[t] = m + __logf(ss);
    __syncthreads();
    float m2 = -INFINITY;
#pragma unroll
    for (int d = -2; d <= 2; d++) {
        int aa = a + d; aa = aa < 0 ? 0 : (aa > 15 ? 15 : aa);
        m2 = fmaxf(m2, sm2[aa * 16 + b]);
    }
    float s2 = 0.f;
#pragma unroll
    for (int d = -2; d <= 2; d++) {
        int aa = a + d; aa = aa < 0 ? 0 : (aa > 15 ? 15 : aa);
        s2 += __expf(sm2[aa * 16 + b] - m2);
    }
    em[base + t] = m2 + __logf(s2) - 3.2188758248682006f;  // log(25)
}

// --------------------- per-(b,t) emission scores ---------------------------
__global__ __launch_bounds__(256) void emis_k(const float* __restrict__ em,
                                              const int* __restrict__ stories,
                                              float* __restrict__ emis)
{
    int bt = blockIdx.x, t = threadIdx.x;
    const int* st = stories + bt * 12;
    int toks[12];
#pragma unroll
    for (int l = 0; l < 12; l++) toks[l] = st[l];
#pragma unroll
    for (int i = 0; i < 8; i++) {
        int s = i * 256 + t;
        float acc = 0.f;
#pragma unroll
        for (int l = 0; l < 12; l++) {
            int tk = toks[l];
            if (tk < 10000) acc += em[(size_t)(bt * 12 + l) * S_TOT + s];
        }
        emis[(size_t)bt * S_TOT + s] = acc;
    }
}

// --------------------- HMM forward recursion -------------------------------
// All 16 emission values + the 8-float transition row preloaded to registers;
// inner loop touches only LDS (score exchange) + VALU.
__global__ __launch_bounds__(1024) void fwd_k(const float* __restrict__ emm,
                                              const float* __restrict__ praw,
                                              const float* __restrict__ plse,
                                              const float* __restrict__ tr,
                                              float* __restrict__ out)
{
    const int OFFS[7] = {0, 1, -1, 16, -16, 256, 512};
    __shared__ float sc[2][S_TOT];
    int b = blockIdx.x, t = threadIdx.x;
    float pl = plse[0];
    const float* eb = emm + (size_t)b * 16 * S_TOT;

    float e[2][16];
#pragma unroll
    for (int i = 0; i < 2; i++) {
        int j = i * 1024 + t;
#pragma unroll
        for (int tt = 0; tt < 16; tt++) e[i][tt] = eb[tt * S_TOT + j];
    }
    float trj[2][7];
#pragma unroll
    for (int i = 0; i < 2; i++) {
        int j = i * 1024 + t;
        float4 lo = ((const float4*)(tr + (size_t)j * 8))[0];
        float4 hi = ((const float4*)(tr + (size_t)j * 8))[1];
        trj[i][0] = lo.x; trj[i][1] = lo.y; trj[i][2] = lo.z; trj[i][3] = lo.w;
        trj[i][4] = hi.x; trj[i][5] = hi.y; trj[i][6] = hi.z;
    }
#pragma unroll
    for (int i = 0; i < 2; i++) {
        int j = i * 1024 + t;
        float v = e[i][0] + praw[j] - pl;
        sc[0][j] = v;
        out[(size_t)b * S_TOT + j] = v;
    }
    __syncthreads();
#pragma unroll
    for (int tt = 1; tt < 16; tt++) {
        int cur = tt & 1, prv = cur ^ 1;
#pragma unroll
        for (int i = 0; i < 2; i++) {
            int j = i * 1024 + t;
            float x[7];
            float m = -INFINITY;
#pragma unroll
            for (int k = 0; k < 7; k++) {
                int ii = j + OFFS[k];
                ii = ii < 0 ? 0 : (ii > 2047 ? 2047 : ii);
                x[k] = trj[i][k] + sc[prv][ii];   // invalid k: trj=-inf -> contributes 0
                m = fmaxf(m, x[k]);
            }
            float ss = 0.f;
#pragma unroll
            for (int k = 0; k < 7; k++) ss += __expf(x[k] - m);
            float v = e[i][tt] + m + __logf(ss);
            sc[cur][j] = v;
            out[(size_t)tt * (8 * S_TOT) + (size_t)b * S_TOT + j] = v;
        }
        __syncthreads();
    }
}

// ---------------------------------------------------------------------------
extern "C" void kernel_launch(void* const* d_in, const int* in_sizes, int n_in,
                              void* d_out, int out_size, void* d_ws, size_t ws_size,
                              hipStream_t stream)
{
    (void)in_sizes; (void)n_in; (void)out_size; (void)ws_size;
    const float* state_emb  = (const float*)d_in[0];
    const float* tok_emb    = (const float*)d_in[1];
    const float* start_w1   = (const float*)d_in[2];
    const float* start_b1   = (const float*)d_in[3];
    const float* start_w2   = (const float*)d_in[4];
    const float* start_b2   = (const float*)d_in[5];
    const float* start_g    = (const float*)d_in[6];
    const float* start_beta = (const float*)d_in[7];
    const float* start_wo   = (const float*)d_in[8];
    const float* start_bo   = (const float*)d_in[9];
    const float* tin_w1     = (const float*)d_in[10];
    const float* tin_b1     = (const float*)d_in[11];
    const float* tin_w2     = (const float*)d_in[12];
    const float* tin_b2     = (const float*)d_in[13];
    const float* tin_g      = (const float*)d_in[14];
    const float* tin_beta   = (const float*)d_in[15];
    const float* tout_w1    = (const float*)d_in[16];
    const float* tout_b1    = (const float*)d_in[17];
    const float* tout_w2    = (const float*)d_in[18];
    const float* tout_b2    = (const float*)d_in[19];
    const float* tout_g     = (const float*)d_in[20];
    const float* tout_beta  = (const float*)d_in[21];
    const float* emit_w1    = (const float*)d_in[22];
    const float* emit_b1    = (const float*)d_in[23];
    const float* emit_w2    = (const float*)d_in[24];
    const float* emit_b2    = (const float*)d_in[25];
    const float* emit_g     = (const float*)d_in[26];
    const float* emit_beta  = (const float*)d_in[27];
    const int*   stories    = (const int*)d_in[28];
    float* out = (float*)d_out;

    char* base = (char*)d_ws;
    size_t off = 0;
    auto carve = [&](size_t bytes) -> char* {
        char* r = base + off;
        off = (off + bytes + 255) & ~(size_t)255;
        return r;
    };

    // ---- persistent region ----
    bf16_t* se_bf   = (bf16_t*)carve((size_t)2048 * 256 * 2);
    bf16_t* tok_bf  = (bf16_t*)carve((size_t)10048 * 128 * 2);
    bf16_t* w_s1    = (bf16_t*)carve((size_t)256 * 256 * 2);
    bf16_t* w_s2    = (bf16_t*)carve((size_t)256 * 256 * 2);
    bf16_t* w_i1    = (bf16_t*)carve((size_t)256 * 256 * 2);
    bf16_t* w_i2    = (bf16_t*)carve((size_t)256 * 256 * 2);
    bf16_t* w_o1    = (bf16_t*)carve((size_t)256 * 256 * 2);
    bf16_t* w_o2    = (bf16_t*)carve((size_t)256 * 256 * 2);
    bf16_t* w_e1    = (bf16_t*)carve((size_t)128 * 256 * 2);
    bf16_t* w_e2    = (bf16_t*)carve((size_t)128 * 128 * 2);
    float*  eb1     = (float*)carve(128 * 4);
    float*  eb2     = (float*)carve(128 * 4);
    bf16_t* hemit   = (bf16_t*)carve((size_t)2048 * 128 * 2);
    float*  hin     = (float*)carve((size_t)2048 * 256 * 4);
    float*  hout    = (float*)carve((size_t)2048 * 256 * 4);
    float*  praw    = (float*)carve((size_t)2048 * 4);
    float*  plse    = (float*)carve(256);
    float*  trans   = (float*)carve((size_t)2048 * 8 * 4);
    bf16_t* tokused = (bf16_t*)carve((size_t)1536 * 128 * 2);
    float*  pmax    = (float*)carve((size_t)NT_LSE * 2048 * 4);
    float*  psum    = (float*)carve((size_t)NT_LSE * 2048 * 4);
    float*  lse     = (float*)carve((size_t)2048 * 4);

    // ---- overlay region: (x1f/x1b/htmp)  vs  (em/emis) — disjoint lifetimes
    size_t ovl = off;
    auto carveA = [&](size_t bytes) -> char* {
        char* r = base + ovl;
        ovl = (ovl + bytes + 255) & ~(size_t)255;
        return r;
    };
    float*  x1f_s  = (float*)carveA((size_t)2048 * 256 * 4);
    float*  x1f_i  = (float*)carveA((size_t)2048 * 256 * 4);
    float*  x1f_o  = (float*)carveA((size_t)2048 * 256 * 4);
    float*  x1f_e  = (float*)carveA((size_t)2048 * 128 * 4);
    bf16_t* x1b_s  = (bf16_t*)carveA((size_t)2048 * 256 * 2);
    bf16_t* x1b_i  = (bf16_t*)carveA((size_t)2048 * 256 * 2);
    bf16_t* x1b_o  = (bf16_t*)carveA((size_t)2048 * 256 * 2);
    bf16_t* x1b_e  = (bf16_t*)carveA((size_t)2048 * 128 * 2);
    float*  htmp_s = (float*)carveA((size_t)2048 * 256 * 4);
    float*  htmp_i = (float*)carveA((size_t)2048 * 256 * 4);
    float*  htmp_o = (float*)carveA((size_t)2048 * 256 * 4);
    float*  htmp_e = (float*)carveA((size_t)2048 * 128 * 4);

    size_t ovlB = off;
    auto carveB = [&](size_t bytes) -> char* {
        char* r = base + ovlB;
        ovlB = (ovlB + bytes + 255) & ~(size_t)255;
        return r;
    };
    float* em   = (float*)carveB((size_t)1536 * 2048 * 4);
    float* emis = (float*)carveB((size_t)128 * 2048 * 4);

    // 1. convert / pad to bf16
    CJobs cj;
    cj.j[0]  = {state_emb, se_bf, 2048, 256, 2048, 256, 1};
    cj.j[1]  = {tok_emb,   tok_bf, 10000, 100, 10048, 128, 1};
    cj.j[2]  = {start_w1,  w_s1, 256, 256, 256, 256, 1};
    cj.j[3]  = {start_w2,  w_s2, 256, 256, 256, 256, 1};
    cj.j[4]  = {tin_w1,    w_i1, 256, 256, 256, 256, 1};
    cj.j[5]  = {tin_w2,    w_i2, 256, 256, 256, 256, 1};
    cj.j[6]  = {tout_w1,   w_o1, 256, 256, 256, 256, 1};
    cj.j[7]  = {tout_w2,   w_o2, 256, 256, 256, 256, 1};
    cj.j[8]  = {emit_w1,   w_e1, 100, 256, 128, 256, 1};
    cj.j[9]  = {emit_w2,   w_e2, 100, 100, 128, 128, 1};
    cj.j[10] = {emit_b1,   eb1, 1, 100, 1, 128, 0};
    cj.j[11] = {emit_b2,   eb2, 1, 100, 1, 128, 0};
    conv_k<<<dim3(160, 12), 256, 0, stream>>>(cj);
    gather_k<<<1536, 128, 0, stream>>>(tok_emb, stories, tokused);

    // 2. stage-1 batched GEMM: x1 = relu(se @ W1^T + b1), all four chains
    GJobs g1;
    g1.j[0] = {se_bf, 256, w_s1, 256, 256, 256, x1f_s, 256, start_b1, nullptr, 0, x1b_s, 256, nullptr, nullptr};
    g1.j[1] = {se_bf, 256, w_i1, 256, 256, 256, x1f_i, 256, tin_b1,   nullptr, 0, x1b_i, 256, nullptr, nullptr};
    g1.j[2] = {se_bf, 256, w_o1, 256, 256, 256, x1f_o, 256, tout_b1,  nullptr, 0, x1b_o, 256, nullptr, nullptr};
    g1.j[3] = {se_bf, 256, w_e1, 256, 128, 256, x1f_e, 128, eb1,      nullptr, 0, x1b_e, 128, nullptr, nullptr};
    gemm_k<1><<<dim3(32, 4, 4), 256, 0, stream>>>(g1);

    // 3. stage-2 batched GEMM: h = relu(x1 @ W2^T + b2) + x1
    GJobs g2;
    g2.j[0] = {x1b_s, 256, w_s2, 256, 256, 256, htmp_s, 256, start_b2, x1f_s, 256, nullptr, 0, nullptr, nullptr};
    g2.j[1] = {x1b_i, 256, w_i2, 256, 256, 256, htmp_i, 256, tin_b2,   x1f_i, 256, nullptr, 0, nullptr, nullptr};
    g2.j[2] = {x1b_o, 256, w_o2, 256, 256, 256, htmp_o, 256, tout_b2,  x1f_o, 256, nullptr, 0, nullptr, nullptr};
    g2.j[3] = {x1b_e, 128, w_e2, 128, 128, 128, htmp_e, 128, eb2,      x1f_e, 128, nullptr, 0, nullptr, nullptr};
    gemm_k<2><<<dim3(32, 4, 4), 256, 0, stream>>>(g2);

    // 4. batched LN (+ fused priors dot for the start chain)
    LJobs lj;
    lj.j[0] = {htmp_s, 256, 256, start_g, start_beta, nullptr, 0, nullptr, 0, 0, start_wo, start_bo, praw};
    lj.j[1] = {htmp_i, 256, 256, tin_g,   tin_beta,   hin, 256, nullptr, 0, 0, nullptr, nullptr, nullptr};
    lj.j[2] = {htmp_o, 256, 256, tout_g,  tout_beta,  hout, 256, nullptr, 0, 0, nullptr, nullptr, nullptr};
    lj.j[3] = {htmp_e, 128, 100, emit_g,  emit_beta,  nullptr, 0, hemit, 128, 128, nullptr, nullptr, nullptr};
    ln_k<<<dim3(2048, 4), 256, 0, stream>>>(lj);

    prior_lse_k<<<1, 1024, 0, stream>>>(praw, plse);
    trans_k<<<512, 256, 0, stream>>>(hin, hout, trans);

    // 5. emission logsumexp over V=10000 (fused GEMM partials) + finalize
    GJobs g3;
    g3.j[0] = {hemit, 128, tok_bf, 128, 10000, 128, nullptr, 0, nullptr, nullptr, 0, nullptr, 0, pmax, psum};
    gemm_k<3><<<dim3(32, NT_LSE, 1), 256, 0, stream>>>(g3);
    lse_fin_k<<<8, 256, 0, stream>>>(pmax, psum, lse);

    // 6. logits at used tokens, pool, per-(b,t) emission scores
    GJobs g0;
    g0.j[0] = {tokused, 128, hemit, 128, 2048, 128, em, 2048, nullptr, nullptr, 0, nullptr, 0, nullptr, nullptr};
    gemm_k<0><<<dim3(24, 32, 1), 256, 0, stream>>>(g0);
    pool_k<<<dim3(1536, 8), 256, 0, stream>>>(em, lse);
    emis_k<<<128, 256, 0, stream>>>(em, stories, emis);

    // 7. forward recursion -> [T,B,S] output
    fwd_k<<<8, 1024, 0, stream>>>(emis, praw, plse, trans, out);
}

// Round 3
// 222.423 us; speedup vs baseline: 1.6292x; 1.3069x over previous
//
#include <hip/hip_runtime.h>
#include <hip/hip_bf16.h>
#include <math.h>

// ---------------------------------------------------------------------------
// Neural3DHMM on MI355X (gfx950) — round 3
//   r2 + transposed LSE partials (coalesced wave-per-state finalize),
//   pool+emis fused, prior-LSE fused into trans_k
// ---------------------------------------------------------------------------

typedef __bf16 bf16_t;
typedef __bf16 bf16x8 __attribute__((ext_vector_type(8)));
typedef float  floatx4 __attribute__((ext_vector_type(4)));
typedef short  short8  __attribute__((ext_vector_type(8)));

#define S_TOT 2048
#define NT_LSE 157   // ceil(10000/64)
#define LSE_LD 160   // padded row stride for Pmax/Psum [s][nb]

// ------------------------------ conversions --------------------------------

struct CJob { const float* src; void* dst; int srows, scols, drows, dcols, tobf; };
struct CJobs { CJob j[12]; };

__global__ void conv_k(CJobs jobs) {
    CJob job = jobs.j[blockIdx.y];
    int total = job.drows * job.dcols;
    for (int idx = blockIdx.x * 256 + threadIdx.x; idx < total; idx += gridDim.x * 256) {
        int r = idx / job.dcols;
        int c = idx - r * job.dcols;
        float v = (r < job.srows && c < job.scols) ? job.src[(size_t)r * job.scols + c] : 0.f;
        if (job.tobf) ((bf16_t*)job.dst)[idx] = (bf16_t)v;
        else          ((float*)job.dst)[idx]  = v;
    }
}

__global__ void gather_k(const float* __restrict__ tok_emb, const int* __restrict__ stories,
                         bf16_t* __restrict__ dst) {
    int j = blockIdx.x;
    int c = threadIdx.x;
    int tok = stories[j];
    float v = (tok < 10000 && c < 100) ? tok_emb[(size_t)tok * 100 + c] : 0.f;
    dst[(size_t)j * 128 + c] = (bf16_t)v;
}

// ------------------------------ bf16 MFMA GEMM (batched) -------------------
struct GJob {
    const bf16_t* A; int lda;
    const bf16_t* Bt; int ldb;
    int N, K;
    float* C; int ldc;
    const float* bias;
    const float* addm; int ldadd;
    bf16_t* Cbf; int ldcb;
    float* Pmax; float* Psum;
};
struct GJobs { GJob j[4]; };

#define BM 64
#define BN 64
#define LDT 72

template<int EPI>
__global__ __launch_bounds__(256) void gemm_k(GJobs jobs) {
    GJob jb = jobs.j[blockIdx.z];
    const int m0 = blockIdx.x * BM;
    const int n0 = blockIdx.y * BN;
    if (n0 >= jb.N) return;

    __shared__ alignas(16) bf16_t As[BM * LDT];
    __shared__ alignas(16) bf16_t Bs[BN * LDT];
    const int tid  = threadIdx.x;
    const int lane = tid & 63, wave = tid >> 6;
    const int wm = (wave & 1) * 32, wn = (wave >> 1) * 32;
    const int sr = tid >> 2, scc = (tid & 3) * 16;
    const int qm = lane & 15, qk = (lane >> 4) * 8;

    floatx4 acc[2][2];
    floatx4 zf = {0.f, 0.f, 0.f, 0.f};
#pragma unroll
    for (int i = 0; i < 2; i++)
#pragma unroll
        for (int j = 0; j < 2; j++) acc[i][j] = zf;

    for (int k0 = 0; k0 < jb.K; k0 += 64) {
        const bf16_t* Ar = jb.A + (size_t)(m0 + sr) * jb.lda + k0 + scc;
        const bf16_t* Br = jb.Bt + (size_t)(n0 + sr) * jb.ldb + k0 + scc;
        *(short8*)&As[sr * LDT + scc]     = *(const short8*)&Ar[0];
        *(short8*)&As[sr * LDT + scc + 8] = *(const short8*)&Ar[8];
        *(short8*)&Bs[sr * LDT + scc]     = *(const short8*)&Br[0];
        *(short8*)&Bs[sr * LDT + scc + 8] = *(const short8*)&Br[8];
        __syncthreads();
#pragma unroll
        for (int kk = 0; kk < 2; kk++) {
            int qo = kk * 32 + qk;
            bf16x8 a[2], b[2];
            a[0] = *(const bf16x8*)&As[(wm + qm) * LDT + qo];
            a[1] = *(const bf16x8*)&As[(wm + 16 + qm) * LDT + qo];
            b[0] = *(const bf16x8*)&Bs[(wn + qm) * LDT + qo];
            b[1] = *(const bf16x8*)&Bs[(wn + 16 + qm) * LDT + qo];
#pragma unroll
            for (int mi = 0; mi < 2; mi++)
#pragma unroll
                for (int ni = 0; ni < 2; ni++)
                    acc[mi][ni] = __builtin_amdgcn_mfma_f32_16x16x32_bf16(a[mi], b[ni], acc[mi][ni], 0, 0, 0);
        }
        __syncthreads();
    }

    const int cl = lane & 15, rq = (lane >> 4) * 4;

    if constexpr (EPI == 3) {
        __shared__ float Cs[BM][BN + 1];
#pragma unroll
        for (int mi = 0; mi < 2; mi++)
#pragma unroll
            for (int ni = 0; ni < 2; ni++)
#pragma unroll
                for (int r = 0; r < 4; r++) {
                    int lm = wm + mi * 16 + rq + r;
                    int ln2 = wn + ni * 16 + cl;
                    Cs[lm][ln2] = (n0 + ln2 < jb.N) ? acc[mi][ni][r] : -INFINITY;
                }
        __syncthreads();
        int trow = tid >> 2, part = tid & 3;
        float m = -INFINITY;
#pragma unroll
        for (int c = 0; c < 16; c++) m = fmaxf(m, Cs[trow][part * 16 + c]);
        m = fmaxf(m, __shfl_xor(m, 1));
        m = fmaxf(m, __shfl_xor(m, 2));
        float ss = 0.f;
#pragma unroll
        for (int c = 0; c < 16; c++) ss += __expf(Cs[trow][part * 16 + c] - m);
        ss += __shfl_xor(ss, 1);
        ss += __shfl_xor(ss, 2);
        if (part == 0) {
            // transposed: [s][nb] — coalesced rows for the finalize kernel
            jb.Pmax[(size_t)(m0 + trow) * LSE_LD + blockIdx.y] = m;
            jb.Psum[(size_t)(m0 + trow) * LSE_LD + blockIdx.y] = ss;
        }
    } else {
#pragma unroll
        for (int mi = 0; mi < 2; mi++)
#pragma unroll
            for (int ni = 0; ni < 2; ni++)
#pragma unroll
                for (int r = 0; r < 4; r++) {
                    int gm = m0 + wm + mi * 16 + rq + r;
                    int gn = n0 + wn + ni * 16 + cl;
                    if (gn < jb.N) {
                        float v = acc[mi][ni][r];
                        if constexpr (EPI == 0) {
                            jb.C[(size_t)gm * jb.ldc + gn] = v;
                        } else if constexpr (EPI == 1) {
                            v = fmaxf(v + jb.bias[gn], 0.f);
                            jb.C[(size_t)gm * jb.ldc + gn] = v;
                            jb.Cbf[(size_t)gm * jb.ldcb + gn] = (bf16_t)v;
                        } else {
                            v = fmaxf(v + jb.bias[gn], 0.f) + jb.addm[(size_t)gm * jb.ldadd + gn];
                            jb.C[(size_t)gm * jb.ldc + gn] = v;
                        }
                    }
                }
    }
}

// ------------------------------ layernorm (batched, praw fused) ------------
struct LJob {
    const float* h; int ld, dout;
    const float* g; const float* beta;
    float* of32; int ldo;
    bf16_t* obf; int ldob; int padN;
    const float* wo; const float* bo; float* praw;
};
struct LJobs { LJob j[4]; };

__global__ __launch_bounds__(256) void ln_k(LJobs jobs) {
    LJob jb = jobs.j[blockIdx.y];
    __shared__ float red[256];
    int row = blockIdx.x, t = threadIdx.x;
    float hv = (t < jb.dout) ? jb.h[(size_t)row * jb.ld + t] : 0.f;
    red[t] = hv;
    __syncthreads();
#pragma unroll
    for (int s = 128; s > 0; s >>= 1) { if (t < s) red[t] += red[t + s]; __syncthreads(); }
    float mu = red[0] / jb.dout;
    __syncthreads();
    float d = (t < jb.dout) ? (hv - mu) : 0.f;
    red[t] = d * d;
    __syncthreads();
#pragma unroll
    for (int s = 128; s > 0; s >>= 1) { if (t < s) red[t] += red[t + s]; __syncthreads(); }
    float var = red[0] / jb.dout;
    float rstd = rsqrtf(var + 1e-5f);
    float y = 0.f;
    if (t < jb.dout) {
        y = d * rstd * jb.g[t] + jb.beta[t];
        if (jb.of32) jb.of32[(size_t)row * jb.ldo + t] = y;
        if (jb.obf)  jb.obf[(size_t)row * jb.ldob + t] = (bf16_t)y;
    } else if (jb.obf && t < jb.padN) {
        jb.obf[(size_t)row * jb.ldob + t] = (bf16_t)0.f;
    }
    if (jb.wo) {
        __syncthreads();
        red[t] = (t < jb.dout) ? y * jb.wo[t] : 0.f;
        __syncthreads();
#pragma unroll
        for (int s = 128; s > 0; s >>= 1) { if (t < s) red[t] += red[t + s]; __syncthreads(); }
        if (t == 0) jb.praw[row] = red[0] + jb.bo[0];
    }
}

// --------- sparse transition (7 neighbors) + fused prior logsumexp ---------
__global__ __launch_bounds__(256) void trans_k(const float* __restrict__ hin,
                                               const float* __restrict__ hout,
                                               float* __restrict__ tr,
                                               const float* __restrict__ praw,
                                               float* __restrict__ plse)
{
    __shared__ float red[256];
    if (blockIdx.x == 512) {
        // prior logsumexp over 2048 entries
        int t = threadIdx.x;
        float v[8];
        float m = -INFINITY;
#pragma unroll
        for (int i = 0; i < 8; i++) { v[i] = praw[t * 8 + i]; m = fmaxf(m, v[i]); }
        red[t] = m;
        __syncthreads();
#pragma unroll
        for (int s = 128; s > 0; s >>= 1) { if (t < s) red[t] = fmaxf(red[t], red[t + s]); __syncthreads(); }
        float M = red[0];
        __syncthreads();
        float ss = 0.f;
#pragma unroll
        for (int i = 0; i < 8; i++) ss += __expf(v[i] - M);
        red[t] = ss;
        __syncthreads();
#pragma unroll
        for (int s = 128; s > 0; s >>= 1) { if (t < s) red[t] += red[t + s]; __syncthreads(); }
        if (t == 0) plse[0] = M + __logf(red[0]);
        return;
    }
    const int OFFS[7] = {0, 1, -1, 16, -16, 256, 512};
    int j = blockIdx.x * 4 + (threadIdx.x >> 6);
    int lane = threadIdx.x & 63;
    float4 a = ((const float4*)(hin + (size_t)j * 256))[lane];
    float d[7];
#pragma unroll
    for (int k = 0; k < 7; k++) {
        int i = j + OFFS[k];
        float pdot = 0.f;
        if ((unsigned)i < 2048u) {
            float4 b = ((const float4*)(hout + (size_t)i * 256))[lane];
            pdot = a.x * b.x + a.y * b.y + a.z * b.z + a.w * b.w;
        }
#pragma unroll
        for (int o = 32; o > 0; o >>= 1) pdot += __shfl_down(pdot, o);
        d[k] = pdot;
    }
    if (lane == 0) {
        float m = -INFINITY;
#pragma unroll
        for (int k = 0; k < 7; k++) { int i = j + OFFS[k]; if ((unsigned)i < 2048u) m = fmaxf(m, d[k]); }
        float ss = 0.f;
#pragma unroll
        for (int k = 0; k < 7; k++) { int i = j + OFFS[k]; if ((unsigned)i < 2048u) ss += __expf(d[k] - m); }
        float l = __logf(ss);
#pragma unroll
        for (int k = 0; k < 7; k++) {
            int i = j + OFFS[k];
            tr[(size_t)j * 8 + k] = ((unsigned)i < 2048u) ? (d[k] - m - l) : -INFINITY;
        }
        tr[(size_t)j * 8 + 7] = -INFINITY;
    }
}

// --------------------- emission logsumexp finalize (wave/state) ------------
__global__ __launch_bounds__(256) void lse_fin_k(const float* __restrict__ Pmax,
                                                 const float* __restrict__ Psum,
                                                 float* __restrict__ lse)
{
    int s = (blockIdx.x * 256 + threadIdx.x) >> 6;   // one wave per state
    int lane = threadIdx.x & 63;
    const float* pm = Pmax + (size_t)s * LSE_LD;
    const float* ps = Psum + (size_t)s * LSE_LD;
    float pv[3], sv[3];
    float m = -INFINITY;
#pragma unroll
    for (int i = 0; i < 3; i++) {
        int nb = i * 64 + lane;
        bool ok = nb < NT_LSE;
        pv[i] = ok ? pm[nb] : -INFINITY;
        sv[i] = ok ? ps[nb] : 0.f;
        m = fmaxf(m, pv[i]);
    }
#pragma unroll
    for (int o = 1; o < 64; o <<= 1) m = fmaxf(m, __shfl_xor(m, o));
    float ss = 0.f;
#pragma unroll
    for (int i = 0; i < 3; i++) ss += sv[i] * __expf(pv[i] - m);
#pragma unroll
    for (int o = 1; o < 64; o <<= 1) ss += __shfl_xor(ss, o);
    if (lane == 0) lse[s] = m + __logf(ss);
}

// ------------- fused 5x5 log-mean pool + per-(b,t) accumulation ------------
// grid (128 bt, 8 z); block 256 covers one z-slab of 256 states.
__global__ __launch_bounds__(256) void poolemis_k(const float* __restrict__ em,
                                                  const float* __restrict__ lse,
                                                  const int* __restrict__ stories,
                                                  float* __restrict__ emis)
{
    __shared__ float sm[256];
    __shared__ float sm2[256];
    int bt = blockIdx.x, z = blockIdx.y, t = threadIdx.x;
    int a = t >> 4, b = t & 15;
    float lsev = lse[z * 256 + t];
    const int* st = stories + bt * 12;
    float acc = 0.f;
    for (int l = 0; l < 12; l++) {
        int tok = st[l];
        size_t base = (size_t)(bt * 12 + l) * S_TOT + (size_t)z * 256;
        float v = em[base + t] - lsev;
        sm[t] = v;
        __syncthreads();
        float m = -INFINITY;
#pragma unroll
        for (int d = -2; d <= 2; d++) {
            int bb = b + d; bb = bb < 0 ? 0 : (bb > 15 ? 15 : bb);
            m = fmaxf(m, sm[a * 16 + bb]);
        }
        float ss = 0.f;
#pragma unroll
        for (int d = -2; d <= 2; d++) {
            int bb = b + d; bb = bb < 0 ? 0 : (bb > 15 ? 15 : bb);
            ss += __expf(sm[a * 16 + bb] - m);
        }
        sm2[t] = m + __logf(ss);
        __syncthreads();
        float m2 = -INFINITY;
#pragma unroll
        for (int d = -2; d <= 2; d++) {
            int aa = a + d; aa = aa < 0 ? 0 : (aa > 15 ? 15 : aa);
            m2 = fmaxf(m2, sm2[aa * 16 + b]);
        }
        float s2 = 0.f;
#pragma unroll
        for (int d = -2; d <= 2; d++) {
            int aa = a + d; aa = aa < 0 ? 0 : (aa > 15 ? 15 : aa);
            s2 += __expf(sm2[aa * 16 + b] - m2);
        }
        if (tok < 10000) acc += m2 + __logf(s2) - 3.2188758248682006f;  // log(25)
        __syncthreads();   // protect sm overwrite next iteration
    }
    emis[(size_t)bt * S_TOT + (size_t)z * 256 + t] = acc;
}

// --------------------- HMM forward recursion -------------------------------
__global__ __launch_bounds__(1024) void fwd_k(const float* __restrict__ emm,
                                              const float* __restrict__ praw,
                                              const float* __restrict__ plse,
                                              const float* __restrict__ tr,
                                              float* __restrict__ out)
{
    const int OFFS[7] = {0, 1, -1, 16, -16, 256, 512};
    __shared__ float sc[2][S_TOT];
    int b = blockIdx.x, t = threadIdx.x;
    float pl = plse[0];
    const float* eb = emm + (size_t)b * 16 * S_TOT;

    float e[2][16];
#pragma unroll
    for (int i = 0; i < 2; i++) {
        int j = i * 1024 + t;
#pragma unroll
        for (int tt = 0; tt < 16; tt++) e[i][tt] = eb[tt * S_TOT + j];
    }
    float trj[2][7];
#pragma unroll
    for (int i = 0; i < 2; i++) {
        int j = i * 1024 + t;
        float4 lo = ((const float4*)(tr + (size_t)j * 8))[0];
        float4 hi = ((const float4*)(tr + (size_t)j * 8))[1];
        trj[i][0] = lo.x; trj[i][1] = lo.y; trj[i][2] = lo.z; trj[i][3] = lo.w;
        trj[i][4] = hi.x; trj[i][5] = hi.y; trj[i][6] = hi.z;
    }
#pragma unroll
    for (int i = 0; i < 2; i++) {
        int j = i * 1024 + t;
        float v = e[i][0] + praw[j] - pl;
        sc[0][j] = v;
        out[(size_t)b * S_TOT + j] = v;
    }
    __syncthreads();
#pragma unroll
    for (int tt = 1; tt < 16; tt++) {
        int cur = tt & 1, prv = cur ^ 1;
#pragma unroll
        for (int i = 0; i < 2; i++) {
            int j = i * 1024 + t;
            float x[7];
            float m = -INFINITY;
#pragma unroll
            for (int k = 0; k < 7; k++) {
                int ii = j + OFFS[k];
                ii = ii < 0 ? 0 : (ii > 2047 ? 2047 : ii);
                x[k] = trj[i][k] + sc[prv][ii];
                m = fmaxf(m, x[k]);
            }
            float ss = 0.f;
#pragma unroll
            for (int k = 0; k < 7; k++) ss += __expf(x[k] - m);
            float v = e[i][tt] + m + __logf(ss);
            sc[cur][j] = v;
            out[(size_t)tt * (8 * S_TOT) + (size_t)b * S_TOT + j] = v;
        }
        __syncthreads();
    }
}

// ---------------------------------------------------------------------------
extern "C" void kernel_launch(void* const* d_in, const int* in_sizes, int n_in,
                              void* d_out, int out_size, void* d_ws, size_t ws_size,
                              hipStream_t stream)
{
    (void)in_sizes; (void)n_in; (void)out_size; (void)ws_size;
    const float* state_emb  = (const float*)d_in[0];
    const float* tok_emb    = (const float*)d_in[1];
    const float* start_w1   = (const float*)d_in[2];
    const float* start_b1   = (const float*)d_in[3];
    const float* start_w2   = (const float*)d_in[4];
    const float* start_b2   = (const float*)d_in[5];
    const float* start_g    = (const float*)d_in[6];
    const float* start_beta = (const float*)d_in[7];
    const float* start_wo   = (const float*)d_in[8];
    const float* start_bo   = (const float*)d_in[9];
    const float* tin_w1     = (const float*)d_in[10];
    const float* tin_b1     = (const float*)d_in[11];
    const float* tin_w2     = (const float*)d_in[12];
    const float* tin_b2     = (const float*)d_in[13];
    const float* tin_g      = (const float*)d_in[14];
    const float* tin_beta   = (const float*)d_in[15];
    const float* tout_w1    = (const float*)d_in[16];
    const float* tout_b1    = (const float*)d_in[17];
    const float* tout_w2    = (const float*)d_in[18];
    const float* tout_b2    = (const float*)d_in[19];
    const float* tout_g     = (const float*)d_in[20];
    const float* tout_beta  = (const float*)d_in[21];
    const float* emit_w1    = (const float*)d_in[22];
    const float* emit_b1    = (const float*)d_in[23];
    const float* emit_w2    = (const float*)d_in[24];
    const float* emit_b2    = (const float*)d_in[25];
    const float* emit_g     = (const float*)d_in[26];
    const float* emit_beta  = (const float*)d_in[27];
    const int*   stories    = (const int*)d_in[28];
    float* out = (float*)d_out;

    char* base = (char*)d_ws;
    size_t off = 0;
    auto carve = [&](size_t bytes) -> char* {
        char* r = base + off;
        off = (off + bytes + 255) & ~(size_t)255;
        return r;
    };

    // ---- persistent region ----
    bf16_t* se_bf   = (bf16_t*)carve((size_t)2048 * 256 * 2);
    bf16_t* tok_bf  = (bf16_t*)carve((size_t)10048 * 128 * 2);
    bf16_t* w_s1    = (bf16_t*)carve((size_t)256 * 256 * 2);
    bf16_t* w_s2    = (bf16_t*)carve((size_t)256 * 256 * 2);
    bf16_t* w_i1    = (bf16_t*)carve((size_t)256 * 256 * 2);
    bf16_t* w_i2    = (bf16_t*)carve((size_t)256 * 256 * 2);
    bf16_t* w_o1    = (bf16_t*)carve((size_t)256 * 256 * 2);
    bf16_t* w_o2    = (bf16_t*)carve((size_t)256 * 256 * 2);
    bf16_t* w_e1    = (bf16_t*)carve((size_t)128 * 256 * 2);
    bf16_t* w_e2    = (bf16_t*)carve((size_t)128 * 128 * 2);
    float*  eb1     = (float*)carve(128 * 4);
    float*  eb2     = (float*)carve(128 * 4);
    bf16_t* hemit   = (bf16_t*)carve((size_t)2048 * 128 * 2);
    float*  hin     = (float*)carve((size_t)2048 * 256 * 4);
    float*  hout    = (float*)carve((size_t)2048 * 256 * 4);
    float*  praw    = (float*)carve((size_t)2048 * 4);
    float*  plse    = (float*)carve(256);
    float*  trans   = (float*)carve((size_t)2048 * 8 * 4);
    bf16_t* tokused = (bf16_t*)carve((size_t)1536 * 128 * 2);
    float*  pmax    = (float*)carve((size_t)2048 * LSE_LD * 4);
    float*  psum    = (float*)carve((size_t)2048 * LSE_LD * 4);
    float*  lse     = (float*)carve((size_t)2048 * 4);

    // ---- overlay region: (x1f/x1b/htmp)  vs  (em/emis) — disjoint lifetimes
    size_t ovl = off;
    auto carveA = [&](size_t bytes) -> char* {
        char* r = base + ovl;
        ovl = (ovl + bytes + 255) & ~(size_t)255;
        return r;
    };
    float*  x1f_s  = (float*)carveA((size_t)2048 * 256 * 4);
    float*  x1f_i  = (float*)carveA((size_t)2048 * 256 * 4);
    float*  x1f_o  = (float*)carveA((size_t)2048 * 256 * 4);
    float*  x1f_e  = (float*)carveA((size_t)2048 * 128 * 4);
    bf16_t* x1b_s  = (bf16_t*)carveA((size_t)2048 * 256 * 2);
    bf16_t* x1b_i  = (bf16_t*)carveA((size_t)2048 * 256 * 2);
    bf16_t* x1b_o  = (bf16_t*)carveA((size_t)2048 * 256 * 2);
    bf16_t* x1b_e  = (bf16_t*)carveA((size_t)2048 * 128 * 2);
    float*  htmp_s = (float*)carveA((size_t)2048 * 256 * 4);
    float*  htmp_i = (float*)carveA((size_t)2048 * 256 * 4);
    float*  htmp_o = (float*)carveA((size_t)2048 * 256 * 4);
    float*  htmp_e = (float*)carveA((size_t)2048 * 128 * 4);

    size_t ovlB = off;
    auto carveB = [&](size_t bytes) -> char* {
        char* r = base + ovlB;
        ovlB = (ovlB + bytes + 255) & ~(size_t)255;
        return r;
    };
    float* em   = (float*)carveB((size_t)1536 * 2048 * 4);
    float* emis = (float*)carveB((size_t)128 * 2048 * 4);

    // 1. convert / pad to bf16
    CJobs cj;
    cj.j[0]  = {state_emb, se_bf, 2048, 256, 2048, 256, 1};
    cj.j[1]  = {tok_emb,   tok_bf, 10000, 100, 10048, 128, 1};
    cj.j[2]  = {start_w1,  w_s1, 256, 256, 256, 256, 1};
    cj.j[3]  = {start_w2,  w_s2, 256, 256, 256, 256, 1};
    cj.j[4]  = {tin_w1,    w_i1, 256, 256, 256, 256, 1};
    cj.j[5]  = {tin_w2,    w_i2, 256, 256, 256, 256, 1};
    cj.j[6]  = {tout_w1,   w_o1, 256, 256, 256, 256, 1};
    cj.j[7]  = {tout_w2,   w_o2, 256, 256, 256, 256, 1};
    cj.j[8]  = {emit_w1,   w_e1, 100, 256, 128, 256, 1};
    cj.j[9]  = {emit_w2,   w_e2, 100, 100, 128, 128, 1};
    cj.j[10] = {emit_b1,   eb1, 1, 100, 1, 128, 0};
    cj.j[11] = {emit_b2,   eb2, 1, 100, 1, 128, 0};
    conv_k<<<dim3(160, 12), 256, 0, stream>>>(cj);
    gather_k<<<1536, 128, 0, stream>>>(tok_emb, stories, tokused);

    // 2. stage-1 batched GEMM
    GJobs g1;
    g1.j[0] = {se_bf, 256, w_s1, 256, 256, 256, x1f_s, 256, start_b1, nullptr, 0, x1b_s, 256, nullptr, nullptr};
    g1.j[1] = {se_bf, 256, w_i1, 256, 256, 256, x1f_i, 256, tin_b1,   nullptr, 0, x1b_i, 256, nullptr, nullptr};
    g1.j[2] = {se_bf, 256, w_o1, 256, 256, 256, x1f_o, 256, tout_b1,  nullptr, 0, x1b_o, 256, nullptr, nullptr};
    g1.j[3] = {se_bf, 256, w_e1, 256, 128, 256, x1f_e, 128, eb1,      nullptr, 0, x1b_e, 128, nullptr, nullptr};
    gemm_k<1><<<dim3(32, 4, 4), 256, 0, stream>>>(g1);

    // 3. stage-2 batched GEMM
    GJobs g2;
    g2.j[0] = {x1b_s, 256, w_s2, 256, 256, 256, htmp_s, 256, start_b2, x1f_s, 256, nullptr, 0, nullptr, nullptr};
    g2.j[1] = {x1b_i, 256, w_i2, 256, 256, 256, htmp_i, 256, tin_b2,   x1f_i, 256, nullptr, 0, nullptr, nullptr};
    g2.j[2] = {x1b_o, 256, w_o2, 256, 256, 256, htmp_o, 256, tout_b2,  x1f_o, 256, nullptr, 0, nullptr, nullptr};
    g2.j[3] = {x1b_e, 128, w_e2, 128, 128, 128, htmp_e, 128, eb2,      x1f_e, 128, nullptr, 0, nullptr, nullptr};
    gemm_k<2><<<dim3(32, 4, 4), 256, 0, stream>>>(g2);

    // 4. batched LN (+ fused priors dot)
    LJobs lj;
    lj.j[0] = {htmp_s, 256, 256, start_g, start_beta, nullptr, 0, nullptr, 0, 0, start_wo, start_bo, praw};
    lj.j[1] = {htmp_i, 256, 256, tin_g,   tin_beta,   hin, 256, nullptr, 0, 0, nullptr, nullptr, nullptr};
    lj.j[2] = {htmp_o, 256, 256, tout_g,  tout_beta,  hout, 256, nullptr, 0, 0, nullptr, nullptr, nullptr};
    lj.j[3] = {htmp_e, 128, 100, emit_g,  emit_beta,  nullptr, 0, hemit, 128, 128, nullptr, nullptr, nullptr};
    ln_k<<<dim3(2048, 4), 256, 0, stream>>>(lj);

    // 5. transition log-softmax + prior LSE (fused, block 512)
    trans_k<<<513, 256, 0, stream>>>(hin, hout, trans, praw, plse);

    // 6. emission logsumexp over V=10000 + finalize
    GJobs g3;
    g3.j[0] = {hemit, 128, tok_bf, 128, 10000, 128, nullptr, 0, nullptr, nullptr, 0, nullptr, 0, pmax, psum};
    gemm_k<3><<<dim3(32, NT_LSE, 1), 256, 0, stream>>>(g3);
    lse_fin_k<<<512, 256, 0, stream>>>(pmax, psum, lse);

    // 7. raw logits at used tokens, fused pool+emis
    GJobs g0;
    g0.j[0] = {tokused, 128, hemit, 128, 2048, 128, em, 2048, nullptr, nullptr, 0, nullptr, 0, nullptr, nullptr};
    gemm_k<0><<<dim3(24, 32, 1), 256, 0, stream>>>(g0);
    poolemis_k<<<dim3(128, 8), 256, 0, stream>>>(em, lse, stories, emis);

    // 8. forward recursion -> [T,B,S] output
    fwd_k<<<8, 1024, 0, stream>>>(emis, praw, plse, trans, out);
}

// Round 4
// 221.770 us; speedup vs baseline: 1.6340x; 1.0029x over previous
//
#include <hip/hip_runtime.h>
#include <hip/hip_bf16.h>
#include <math.h>

// ---------------------------------------------------------------------------
// Neural3DHMM on MI355X (gfx950) — round 4
//   r3 + fused em-GEMM/pool/emis (empool_k): no em round-trip, no gather_k
//   9 launches: conv, gemm1, gemm2, ln, trans(+plse), gemm3, lse_fin,
//               empool, fwd
// ---------------------------------------------------------------------------

typedef __bf16 bf16_t;
typedef __bf16 bf16x8 __attribute__((ext_vector_type(8)));
typedef float  floatx4 __attribute__((ext_vector_type(4)));
typedef short  short8  __attribute__((ext_vector_type(8)));

#define S_TOT 2048
#define NT_LSE 157   // ceil(10000/64)
#define LSE_LD 160   // padded row stride for Pmax/Psum [s][nb]

// ------------------------------ conversions --------------------------------

struct CJob { const float* src; void* dst; int srows, scols, drows, dcols, tobf; };
struct CJobs { CJob j[12]; };

__global__ void conv_k(CJobs jobs) {
    CJob job = jobs.j[blockIdx.y];
    int total = job.drows * job.dcols;
    for (int idx = blockIdx.x * 256 + threadIdx.x; idx < total; idx += gridDim.x * 256) {
        int r = idx / job.dcols;
        int c = idx - r * job.dcols;
        float v = (r < job.srows && c < job.scols) ? job.src[(size_t)r * job.scols + c] : 0.f;
        if (job.tobf) ((bf16_t*)job.dst)[idx] = (bf16_t)v;
        else          ((float*)job.dst)[idx]  = v;
    }
}

// ------------------------------ bf16 MFMA GEMM (batched) -------------------
struct GJob {
    const bf16_t* A; int lda;
    const bf16_t* Bt; int ldb;
    int N, K;
    float* C; int ldc;
    const float* bias;
    const float* addm; int ldadd;
    bf16_t* Cbf; int ldcb;
    float* Pmax; float* Psum;
};
struct GJobs { GJob j[4]; };

#define BM 64
#define BN 64
#define LDT 72

template<int EPI>
__global__ __launch_bounds__(256) void gemm_k(GJobs jobs) {
    GJob jb = jobs.j[blockIdx.z];
    const int m0 = blockIdx.x * BM;
    const int n0 = blockIdx.y * BN;
    if (n0 >= jb.N) return;

    __shared__ alignas(16) bf16_t As[BM * LDT];
    __shared__ alignas(16) bf16_t Bs[BN * LDT];
    const int tid  = threadIdx.x;
    const int lane = tid & 63, wave = tid >> 6;
    const int wm = (wave & 1) * 32, wn = (wave >> 1) * 32;
    const int sr = tid >> 2, scc = (tid & 3) * 16;
    const int qm = lane & 15, qk = (lane >> 4) * 8;

    floatx4 acc[2][2];
    floatx4 zf = {0.f, 0.f, 0.f, 0.f};
#pragma unroll
    for (int i = 0; i < 2; i++)
#pragma unroll
        for (int j = 0; j < 2; j++) acc[i][j] = zf;

    for (int k0 = 0; k0 < jb.K; k0 += 64) {
        const bf16_t* Ar = jb.A + (size_t)(m0 + sr) * jb.lda + k0 + scc;
        const bf16_t* Br = jb.Bt + (size_t)(n0 + sr) * jb.ldb + k0 + scc;
        *(short8*)&As[sr * LDT + scc]     = *(const short8*)&Ar[0];
        *(short8*)&As[sr * LDT + scc + 8] = *(const short8*)&Ar[8];
        *(short8*)&Bs[sr * LDT + scc]     = *(const short8*)&Br[0];
        *(short8*)&Bs[sr * LDT + scc + 8] = *(const short8*)&Br[8];
        __syncthreads();
#pragma unroll
        for (int kk = 0; kk < 2; kk++) {
            int qo = kk * 32 + qk;
            bf16x8 a[2], b[2];
            a[0] = *(const bf16x8*)&As[(wm + qm) * LDT + qo];
            a[1] = *(const bf16x8*)&As[(wm + 16 + qm) * LDT + qo];
            b[0] = *(const bf16x8*)&Bs[(wn + qm) * LDT + qo];
            b[1] = *(const bf16x8*)&Bs[(wn + 16 + qm) * LDT + qo];
#pragma unroll
            for (int mi = 0; mi < 2; mi++)
#pragma unroll
                for (int ni = 0; ni < 2; ni++)
                    acc[mi][ni] = __builtin_amdgcn_mfma_f32_16x16x32_bf16(a[mi], b[ni], acc[mi][ni], 0, 0, 0);
        }
        __syncthreads();
    }

    const int cl = lane & 15, rq = (lane >> 4) * 4;

    if constexpr (EPI == 3) {
        __shared__ float Cs[BM][BN + 1];
#pragma unroll
        for (int mi = 0; mi < 2; mi++)
#pragma unroll
            for (int ni = 0; ni < 2; ni++)
#pragma unroll
                for (int r = 0; r < 4; r++) {
                    int lm = wm + mi * 16 + rq + r;
                    int ln2 = wn + ni * 16 + cl;
                    Cs[lm][ln2] = (n0 + ln2 < jb.N) ? acc[mi][ni][r] : -INFINITY;
                }
        __syncthreads();
        int trow = tid >> 2, part = tid & 3;
        float m = -INFINITY;
#pragma unroll
        for (int c = 0; c < 16; c++) m = fmaxf(m, Cs[trow][part * 16 + c]);
        m = fmaxf(m, __shfl_xor(m, 1));
        m = fmaxf(m, __shfl_xor(m, 2));
        float ss = 0.f;
#pragma unroll
        for (int c = 0; c < 16; c++) ss += __expf(Cs[trow][part * 16 + c] - m);
        ss += __shfl_xor(ss, 1);
        ss += __shfl_xor(ss, 2);
        if (part == 0) {
            // transposed: [s][nb] — coalesced rows for the finalize kernel
            jb.Pmax[(size_t)(m0 + trow) * LSE_LD + blockIdx.y] = m;
            jb.Psum[(size_t)(m0 + trow) * LSE_LD + blockIdx.y] = ss;
        }
    } else {
#pragma unroll
        for (int mi = 0; mi < 2; mi++)
#pragma unroll
            for (int ni = 0; ni < 2; ni++)
#pragma unroll
                for (int r = 0; r < 4; r++) {
                    int gm = m0 + wm + mi * 16 + rq + r;
                    int gn = n0 + wn + ni * 16 + cl;
                    if (gn < jb.N) {
                        float v = acc[mi][ni][r];
                        if constexpr (EPI == 0) {
                            jb.C[(size_t)gm * jb.ldc + gn] = v;
                        } else if constexpr (EPI == 1) {
                            v = fmaxf(v + jb.bias[gn], 0.f);
                            jb.C[(size_t)gm * jb.ldc + gn] = v;
                            jb.Cbf[(size_t)gm * jb.ldcb + gn] = (bf16_t)v;
                        } else {
                            v = fmaxf(v + jb.bias[gn], 0.f) + jb.addm[(size_t)gm * jb.ldadd + gn];
                            jb.C[(size_t)gm * jb.ldc + gn] = v;
                        }
                    }
                }
    }
}

// ------------------------------ layernorm (batched, praw fused) ------------
struct LJob {
    const float* h; int ld, dout;
    const float* g; const float* beta;
    float* of32; int ldo;
    bf16_t* obf; int ldob; int padN;
    const float* wo; const float* bo; float* praw;
};
struct LJobs { LJob j[4]; };

__global__ __launch_bounds__(256) void ln_k(LJobs jobs) {
    LJob jb = jobs.j[blockIdx.y];
    __shared__ float red[256];
    int row = blockIdx.x, t = threadIdx.x;
    float hv = (t < jb.dout) ? jb.h[(size_t)row * jb.ld + t] : 0.f;
    red[t] = hv;
    __syncthreads();
#pragma unroll
    for (int s = 128; s > 0; s >>= 1) { if (t < s) red[t] += red[t + s]; __syncthreads(); }
    float mu = red[0] / jb.dout;
    __syncthreads();
    float d = (t < jb.dout) ? (hv - mu) : 0.f;
    red[t] = d * d;
    __syncthreads();
#pragma unroll
    for (int s = 128; s > 0; s >>= 1) { if (t < s) red[t] += red[t + s]; __syncthreads(); }
    float var = red[0] / jb.dout;
    float rstd = rsqrtf(var + 1e-5f);
    float y = 0.f;
    if (t < jb.dout) {
        y = d * rstd * jb.g[t] + jb.beta[t];
        if (jb.of32) jb.of32[(size_t)row * jb.ldo + t] = y;
        if (jb.obf)  jb.obf[(size_t)row * jb.ldob + t] = (bf16_t)y;
    } else if (jb.obf && t < jb.padN) {
        jb.obf[(size_t)row * jb.ldob + t] = (bf16_t)0.f;
    }
    if (jb.wo) {
        __syncthreads();
        red[t] = (t < jb.dout) ? y * jb.wo[t] : 0.f;
        __syncthreads();
#pragma unroll
        for (int s = 128; s > 0; s >>= 1) { if (t < s) red[t] += red[t + s]; __syncthreads(); }
        if (t == 0) jb.praw[row] = red[0] + jb.bo[0];
    }
}

// --------- sparse transition (7 neighbors) + fused prior logsumexp ---------
__global__ __launch_bounds__(256) void trans_k(const float* __restrict__ hin,
                                               const float* __restrict__ hout,
                                               float* __restrict__ tr,
                                               const float* __restrict__ praw,
                                               float* __restrict__ plse)
{
    __shared__ float red[256];
    if (blockIdx.x == 512) {
        int t = threadIdx.x;
        float v[8];
        float m = -INFINITY;
#pragma unroll
        for (int i = 0; i < 8; i++) { v[i] = praw[t * 8 + i]; m = fmaxf(m, v[i]); }
        red[t] = m;
        __syncthreads();
#pragma unroll
        for (int s = 128; s > 0; s >>= 1) { if (t < s) red[t] = fmaxf(red[t], red[t + s]); __syncthreads(); }
        float M = red[0];
        __syncthreads();
        float ss = 0.f;
#pragma unroll
        for (int i = 0; i < 8; i++) ss += __expf(v[i] - M);
        red[t] = ss;
        __syncthreads();
#pragma unroll
        for (int s = 128; s > 0; s >>= 1) { if (t < s) red[t] += red[t + s]; __syncthreads(); }
        if (t == 0) plse[0] = M + __logf(red[0]);
        return;
    }
    const int OFFS[7] = {0, 1, -1, 16, -16, 256, 512};
    int j = blockIdx.x * 4 + (threadIdx.x >> 6);
    int lane = threadIdx.x & 63;
    float4 a = ((const float4*)(hin + (size_t)j * 256))[lane];
    float d[7];
#pragma unroll
    for (int k = 0; k < 7; k++) {
        int i = j + OFFS[k];
        float pdot = 0.f;
        if ((unsigned)i < 2048u) {
            float4 b = ((const float4*)(hout + (size_t)i * 256))[lane];
            pdot = a.x * b.x + a.y * b.y + a.z * b.z + a.w * b.w;
        }
#pragma unroll
        for (int o = 32; o > 0; o >>= 1) pdot += __shfl_down(pdot, o);
        d[k] = pdot;
    }
    if (lane == 0) {
        float m = -INFINITY;
#pragma unroll
        for (int k = 0; k < 7; k++) { int i = j + OFFS[k]; if ((unsigned)i < 2048u) m = fmaxf(m, d[k]); }
        float ss = 0.f;
#pragma unroll
        for (int k = 0; k < 7; k++) { int i = j + OFFS[k]; if ((unsigned)i < 2048u) ss += __expf(d[k] - m); }
        float l = __logf(ss);
#pragma unroll
        for (int k = 0; k < 7; k++) {
            int i = j + OFFS[k];
            tr[(size_t)j * 8 + k] = ((unsigned)i < 2048u) ? (d[k] - m - l) : -INFINITY;
        }
        tr[(size_t)j * 8 + 7] = -INFINITY;
    }
}

// --------------------- emission logsumexp finalize (wave/state) ------------
__global__ __launch_bounds__(256) void lse_fin_k(const float* __restrict__ Pmax,
                                                 const float* __restrict__ Psum,
                                                 float* __restrict__ lse)
{
    int s = (blockIdx.x * 256 + threadIdx.x) >> 6;   // one wave per state
    int lane = threadIdx.x & 63;
    const float* pm = Pmax + (size_t)s * LSE_LD;
    const float* ps = Psum + (size_t)s * LSE_LD;
    float pv[3], sv[3];
    float m = -INFINITY;
#pragma unroll
    for (int i = 0; i < 3; i++) {
        int nb = i * 64 + lane;
        bool ok = nb < NT_LSE;
        pv[i] = ok ? pm[nb] : -INFINITY;
        sv[i] = ok ? ps[nb] : 0.f;
        m = fmaxf(m, pv[i]);
    }
#pragma unroll
    for (int o = 1; o < 64; o <<= 1) m = fmaxf(m, __shfl_xor(m, o));
    float ss = 0.f;
#pragma unroll
    for (int i = 0; i < 3; i++) ss += sv[i] * __expf(pv[i] - m);
#pragma unroll
    for (int o = 1; o < 64; o <<= 1) ss += __shfl_xor(ss, o);
    if (lane == 0) lse[s] = m + __logf(ss);
}

// ---- fused: em tile MFMA (12 tokens x 256 states) + 5x5 pool + emis -------
// grid (128 bt, 8 z); block 256 = 4 waves; each wave computes 4 n-tiles.
#define ELDT 136
__global__ __launch_bounds__(256) void empool_k(
    const float* __restrict__ tok_emb, const int* __restrict__ stories,
    const bf16_t* __restrict__ hemit, const float* __restrict__ lse,
    float* __restrict__ emis)
{
    __shared__ alignas(16) bf16_t As[16 * ELDT];
    __shared__ float Cs[16][260];
    __shared__ float sm2[256];
    __shared__ int stok[12];
    const int bt = blockIdx.x, z = blockIdx.y, t = threadIdx.x;
    if (t < 12) stok[t] = stories[bt * 12 + t];
    __syncthreads();
    // stage A: 16 rows (12 tokens + 4 zero pad) x 128 cols, bf16
    {
        int row = t >> 4, c0 = (t & 15) * 8;
        int tok = (row < 12) ? stok[row] : 10000;
        const float* src = tok_emb + (size_t)tok * 100;
#pragma unroll
        for (int c = 0; c < 8; c++) {
            int cc = c0 + c;
            float v = (tok < 10000 && cc < 100) ? src[cc] : 0.f;
            As[row * ELDT + cc] = (bf16_t)v;
        }
    }
    __syncthreads();

    const int lane = t & 63, wave = t >> 6;
    const int qm = lane & 15, q = lane >> 4;
    floatx4 acc[4];
    floatx4 zf = {0.f, 0.f, 0.f, 0.f};
#pragma unroll
    for (int j = 0; j < 4; j++) acc[j] = zf;

#pragma unroll
    for (int kk = 0; kk < 4; kk++) {
        bf16x8 a = *(const bf16x8*)&As[qm * ELDT + kk * 32 + q * 8];
#pragma unroll
        for (int j = 0; j < 4; j++) {
            int nrow = z * 256 + (wave * 4 + j) * 16 + qm;
            bf16x8 b = *(const bf16x8*)&hemit[(size_t)nrow * 128 + kk * 32 + q * 8];
            acc[j] = __builtin_amdgcn_mfma_f32_16x16x32_bf16(a, b, acc[j], 0, 0, 0);
        }
    }
    // epilogue: Cs[slot][state-in-slab] = logit - lse  (log_softmax numerator)
    {
        const int cl = lane & 15, rq = (lane >> 4) * 4;
#pragma unroll
        for (int j = 0; j < 4; j++) {
            int n = (wave * 4 + j) * 16 + cl;
            float ls = lse[z * 256 + n];
#pragma unroll
            for (int r = 0; r < 4; r++)
                Cs[rq + r][n] = acc[j][r] - ls;
        }
    }
    __syncthreads();

    // 5x5 replicate-pad log-mean pool (b-dir then a-dir), accumulate 12 slots
    const int a = t >> 4, b = t & 15;
    float accum = 0.f;
    for (int l = 0; l < 12; l++) {
        float m = -INFINITY;
#pragma unroll
        for (int d = -2; d <= 2; d++) {
            int bb = b + d; bb = bb < 0 ? 0 : (bb > 15 ? 15 : bb);
            m = fmaxf(m, Cs[l][a * 16 + bb]);
        }
        float ss = 0.f;
#pragma unroll
        for (int d = -2; d <= 2; d++) {
            int bb = b + d; bb = bb < 0 ? 0 : (bb > 15 ? 15 : bb);
            ss += __expf(Cs[l][a * 16 + bb] - m);
        }
        sm2[t] = m + __logf(ss);
        __syncthreads();
        float m2 = -INFINITY;
#pragma unroll
        for (int d = -2; d <= 2; d++) {
            int aa = a + d; aa = aa < 0 ? 0 : (aa > 15 ? 15 : aa);
            m2 = fmaxf(m2, sm2[aa * 16 + b]);
        }
        float s2 = 0.f;
#pragma unroll
        for (int d = -2; d <= 2; d++) {
            int aa = a + d; aa = aa < 0 ? 0 : (aa > 15 ? 15 : aa);
            s2 += __expf(sm2[aa * 16 + b] - m2);
        }
        if (stok[l] < 10000) accum += m2 + __logf(s2) - 3.2188758248682006f;  // log(25)
        __syncthreads();
    }
    emis[(size_t)bt * S_TOT + (size_t)z * 256 + t] = accum;
}

// --------------------- HMM forward recursion -------------------------------
__global__ __launch_bounds__(1024) void fwd_k(const float* __restrict__ emm,
                                              const float* __restrict__ praw,
                                              const float* __restrict__ plse,
                                              const float* __restrict__ tr,
                                              float* __restrict__ out)
{
    const int OFFS[7] = {0, 1, -1, 16, -16, 256, 512};
    __shared__ float sc[2][S_TOT];
    int b = blockIdx.x, t = threadIdx.x;
    float pl = plse[0];
    const float* eb = emm + (size_t)b * 16 * S_TOT;

    float e[2][16];
#pragma unroll
    for (int i = 0; i < 2; i++) {
        int j = i * 1024 + t;
#pragma unroll
        for (int tt = 0; tt < 16; tt++) e[i][tt] = eb[tt * S_TOT + j];
    }
    float trj[2][7];
#pragma unroll
    for (int i = 0; i < 2; i++) {
        int j = i * 1024 + t;
        float4 lo = ((const float4*)(tr + (size_t)j * 8))[0];
        float4 hi = ((const float4*)(tr + (size_t)j * 8))[1];
        trj[i][0] = lo.x; trj[i][1] = lo.y; trj[i][2] = lo.z; trj[i][3] = lo.w;
        trj[i][4] = hi.x; trj[i][5] = hi.y; trj[i][6] = hi.z;
    }
#pragma unroll
    for (int i = 0; i < 2; i++) {
        int j = i * 1024 + t;
        float v = e[i][0] + praw[j] - pl;
        sc[0][j] = v;
        out[(size_t)b * S_TOT + j] = v;
    }
    __syncthreads();
#pragma unroll
    for (int tt = 1; tt < 16; tt++) {
        int cur = tt & 1, prv = cur ^ 1;
#pragma unroll
        for (int i = 0; i < 2; i++) {
            int j = i * 1024 + t;
            float x[7];
            float m = -INFINITY;
#pragma unroll
            for (int k = 0; k < 7; k++) {
                int ii = j + OFFS[k];
                ii = ii < 0 ? 0 : (ii > 2047 ? 2047 : ii);
                x[k] = trj[i][k] + sc[prv][ii];
                m = fmaxf(m, x[k]);
            }
            float ss = 0.f;
#pragma unroll
            for (int k = 0; k < 7; k++) ss += __expf(x[k] - m);
            float v = e[i][tt] + m + __logf(ss);
            sc[cur][j] = v;
            out[(size_t)tt * (8 * S_TOT) + (size_t)b * S_TOT + j] = v;
        }
        __syncthreads();
    }
}

// ---------------------------------------------------------------------------
extern "C" void kernel_launch(void* const* d_in, const int* in_sizes, int n_in,
                              void* d_out, int out_size, void* d_ws, size_t ws_size,
                              hipStream_t stream)
{
    (void)in_sizes; (void)n_in; (void)out_size; (void)ws_size;
    const float* state_emb  = (const float*)d_in[0];
    const float* tok_emb    = (const float*)d_in[1];
    const float* start_w1   = (const float*)d_in[2];
    const float* start_b1   = (const float*)d_in[3];
    const float* start_w2   = (const float*)d_in[4];
    const float* start_b2   = (const float*)d_in[5];
    const float* start_g    = (const float*)d_in[6];
    const float* start_beta = (const float*)d_in[7];
    const float* start_wo   = (const float*)d_in[8];
    const float* start_bo   = (const float*)d_in[9];
    const float* tin_w1     = (const float*)d_in[10];
    const float* tin_b1     = (const float*)d_in[11];
    const float* tin_w2     = (const float*)d_in[12];
    const float* tin_b2     = (const float*)d_in[13];
    const float* tin_g      = (const float*)d_in[14];
    const float* tin_beta   = (const float*)d_in[15];
    const float* tout_w1    = (const float*)d_in[16];
    const float* tout_b1    = (const float*)d_in[17];
    const float* tout_w2    = (const float*)d_in[18];
    const float* tout_b2    = (const float*)d_in[19];
    const float* tout_g     = (const float*)d_in[20];
    const float* tout_beta  = (const float*)d_in[21];
    const float* emit_w1    = (const float*)d_in[22];
    const float* emit_b1    = (const float*)d_in[23];
    const float* emit_w2    = (const float*)d_in[24];
    const float* emit_b2    = (const float*)d_in[25];
    const float* emit_g     = (const float*)d_in[26];
    const float* emit_beta  = (const float*)d_in[27];
    const int*   stories    = (const int*)d_in[28];
    float* out = (float*)d_out;

    char* base = (char*)d_ws;
    size_t off = 0;
    auto carve = [&](size_t bytes) -> char* {
        char* r = base + off;
        off = (off + bytes + 255) & ~(size_t)255;
        return r;
    };

    // ---- persistent region ----
    bf16_t* se_bf   = (bf16_t*)carve((size_t)2048 * 256 * 2);
    bf16_t* tok_bf  = (bf16_t*)carve((size_t)10048 * 128 * 2);
    bf16_t* w_s1    = (bf16_t*)carve((size_t)256 * 256 * 2);
    bf16_t* w_s2    = (bf16_t*)carve((size_t)256 * 256 * 2);
    bf16_t* w_i1    = (bf16_t*)carve((size_t)256 * 256 * 2);
    bf16_t* w_i2    = (bf16_t*)carve((size_t)256 * 256 * 2);
    bf16_t* w_o1    = (bf16_t*)carve((size_t)256 * 256 * 2);
    bf16_t* w_o2    = (bf16_t*)carve((size_t)256 * 256 * 2);
    bf16_t* w_e1    = (bf16_t*)carve((size_t)128 * 256 * 2);
    bf16_t* w_e2    = (bf16_t*)carve((size_t)128 * 128 * 2);
    float*  eb1     = (float*)carve(128 * 4);
    float*  eb2     = (float*)carve(128 * 4);
    bf16_t* hemit   = (bf16_t*)carve((size_t)2048 * 128 * 2);
    float*  hin     = (float*)carve((size_t)2048 * 256 * 4);
    float*  hout    = (float*)carve((size_t)2048 * 256 * 4);
    float*  praw    = (float*)carve((size_t)2048 * 4);
    float*  plse    = (float*)carve(256);
    float*  trans   = (float*)carve((size_t)2048 * 8 * 4);
    float*  pmax    = (float*)carve((size_t)2048 * LSE_LD * 4);
    float*  psum    = (float*)carve((size_t)2048 * LSE_LD * 4);
    float*  lse     = (float*)carve((size_t)2048 * 4);
    float*  emis    = (float*)carve((size_t)128 * 2048 * 4);

    // ---- overlay region: stage-1/2 temps (dead after ln_k) ----
    size_t ovl = off;
    auto carveA = [&](size_t bytes) -> char* {
        char* r = base + ovl;
        ovl = (ovl + bytes + 255) & ~(size_t)255;
        return r;
    };
    float*  x1f_s  = (float*)carveA((size_t)2048 * 256 * 4);
    float*  x1f_i  = (float*)carveA((size_t)2048 * 256 * 4);
    float*  x1f_o  = (float*)carveA((size_t)2048 * 256 * 4);
    float*  x1f_e  = (float*)carveA((size_t)2048 * 128 * 4);
    bf16_t* x1b_s  = (bf16_t*)carveA((size_t)2048 * 256 * 2);
    bf16_t* x1b_i  = (bf16_t*)carveA((size_t)2048 * 256 * 2);
    bf16_t* x1b_o  = (bf16_t*)carveA((size_t)2048 * 256 * 2);
    bf16_t* x1b_e  = (bf16_t*)carveA((size_t)2048 * 128 * 2);
    float*  htmp_s = (float*)carveA((size_t)2048 * 256 * 4);
    float*  htmp_i = (float*)carveA((size_t)2048 * 256 * 4);
    float*  htmp_o = (float*)carveA((size_t)2048 * 256 * 4);
    float*  htmp_e = (float*)carveA((size_t)2048 * 128 * 4);

    // 1. convert / pad to bf16
    CJobs cj;
    cj.j[0]  = {state_emb, se_bf, 2048, 256, 2048, 256, 1};
    cj.j[1]  = {tok_emb,   tok_bf, 10000, 100, 10048, 128, 1};
    cj.j[2]  = {start_w1,  w_s1, 256, 256, 256, 256, 1};
    cj.j[3]  = {start_w2,  w_s2, 256, 256, 256, 256, 1};
    cj.j[4]  = {tin_w1,    w_i1, 256, 256, 256, 256, 1};
    cj.j[5]  = {tin_w2,    w_i2, 256, 256, 256, 256, 1};
    cj.j[6]  = {tout_w1,   w_o1, 256, 256, 256, 256, 1};
    cj.j[7]  = {tout_w2,   w_o2, 256, 256, 256, 256, 1};
    cj.j[8]  = {emit_w1,   w_e1, 100, 256, 128, 256, 1};
    cj.j[9]  = {emit_w2,   w_e2, 100, 100, 128, 128, 1};
    cj.j[10] = {emit_b1,   eb1, 1, 100, 1, 128, 0};
    cj.j[11] = {emit_b2,   eb2, 1, 100, 1, 128, 0};
    conv_k<<<dim3(160, 12), 256, 0, stream>>>(cj);

    // 2. stage-1 batched GEMM
    GJobs g1;
    g1.j[0] = {se_bf, 256, w_s1, 256, 256, 256, x1f_s, 256, start_b1, nullptr, 0, x1b_s, 256, nullptr, nullptr};
    g1.j[1] = {se_bf, 256, w_i1, 256, 256, 256, x1f_i, 256, tin_b1,   nullptr, 0, x1b_i, 256, nullptr, nullptr};
    g1.j[2] = {se_bf, 256, w_o1, 256, 256, 256, x1f_o, 256, tout_b1,  nullptr, 0, x1b_o, 256, nullptr, nullptr};
    g1.j[3] = {se_bf, 256, w_e1, 256, 128, 256, x1f_e, 128, eb1,      nullptr, 0, x1b_e, 128, nullptr, nullptr};
    gemm_k<1><<<dim3(32, 4, 4), 256, 0, stream>>>(g1);

    // 3. stage-2 batched GEMM
    GJobs g2;
    g2.j[0] = {x1b_s, 256, w_s2, 256, 256, 256, htmp_s, 256, start_b2, x1f_s, 256, nullptr, 0, nullptr, nullptr};
    g2.j[1] = {x1b_i, 256, w_i2, 256, 256, 256, htmp_i, 256, tin_b2,   x1f_i, 256, nullptr, 0, nullptr, nullptr};
    g2.j[2] = {x1b_o, 256, w_o2, 256, 256, 256, htmp_o, 256, tout_b2,  x1f_o, 256, nullptr, 0, nullptr, nullptr};
    g2.j[3] = {x1b_e, 128, w_e2, 128, 128, 128, htmp_e, 128, eb2,      x1f_e, 128, nullptr, 0, nullptr, nullptr};
    gemm_k<2><<<dim3(32, 4, 4), 256, 0, stream>>>(g2);

    // 4. batched LN (+ fused priors dot)
    LJobs lj;
    lj.j[0] = {htmp_s, 256, 256, start_g, start_beta, nullptr, 0, nullptr, 0, 0, start_wo, start_bo, praw};
    lj.j[1] = {htmp_i, 256, 256, tin_g,   tin_beta,   hin, 256, nullptr, 0, 0, nullptr, nullptr, nullptr};
    lj.j[2] = {htmp_o, 256, 256, tout_g,  tout_beta,  hout, 256, nullptr, 0, 0, nullptr, nullptr, nullptr};
    lj.j[3] = {htmp_e, 128, 100, emit_g,  emit_beta,  nullptr, 0, hemit, 128, 128, nullptr, nullptr, nullptr};
    ln_k<<<dim3(2048, 4), 256, 0, stream>>>(lj);

    // 5. transition log-softmax + prior LSE (fused, block 512)
    trans_k<<<513, 256, 0, stream>>>(hin, hout, trans, praw, plse);

    // 6. emission logsumexp over V=10000 + finalize
    GJobs g3;
    g3.j[0] = {hemit, 128, tok_bf, 128, 10000, 128, nullptr, 0, nullptr, nullptr, 0, nullptr, 0, pmax, psum};
    gemm_k<3><<<dim3(32, NT_LSE, 1), 256, 0, stream>>>(g3);
    lse_fin_k<<<512, 256, 0, stream>>>(pmax, psum, lse);

    // 7. fused em-GEMM + pool + emis
    empool_k<<<dim3(128, 8), 256, 0, stream>>>(tok_emb, stories, hemit, lse, emis);

    // 8. forward recursion -> [T,B,S] output
    fwd_k<<<8, 1024, 0, stream>>>(emis, praw, plse, trans, out);
}